// Round 15
// baseline (411.246 us; speedup 1.0000x reference)
//
#include <hip/hip_runtime.h>
#include <hip/hip_fp16.h>
#include <math.h>

constexpr int NN  = 50000;   // nodes
constexpr int EE  = 800000;  // edges
constexpr int INF_ = 256;    // input feat
constexpr int HF  = 128;     // hidden
constexpr int CC  = 50;      // classes
constexpr long NH = (long)NN * HF;
constexpr int NSL = 32;          // edge slices (preprocessing)
constexpr int ESL = EE / NSL;    // 25000 edges per slice
constexpr int CHK = 12500;       // nodes per chunk (4 chunks), 50KB LDS
#define EPSV 1e-5f

enum { EPI_RELU = 0, EPI_NONE = 1, EPI_BN = 2, EPI_BN_RES = 3, EPI_ATTN = 4 };
enum { H16_NONE = 0, H16_SCALED = 2 };

typedef __attribute__((ext_vector_type(4))) float f32x4;
typedef __attribute__((ext_vector_type(8))) _Float16 f16x8;

// ---------------- graph preprocessing (atomic-free: LDS histograms) ----------------

__global__ __launch_bounds__(256) void count_partial2_kernel(
    const int4* __restrict__ dst4, const int4* __restrict__ src4,
    unsigned* __restrict__ pd, unsigned* __restrict__ ps) {
  __shared__ unsigned cnt[CHK];
  int bb = blockIdx.x;
  const int which = bb >> 7;
  bb &= 127;
  const int4* keys4 = which ? src4 : dst4;
  unsigned* partials = which ? ps : pd;
  const int chunk = bb & 3;
  const int sl = bb >> 2;
  for (int i = threadIdx.x; i < CHK; i += 256) cnt[i] = 0;
  __syncthreads();
  const int base4 = sl * (ESL / 4);
  const int lo = chunk * CHK;
  for (int i = threadIdx.x; i < ESL / 4; i += 256) {
    int4 k = keys4[base4 + i];
    int a;
    a = k.x - lo; if ((unsigned)a < (unsigned)CHK) atomicAdd(&cnt[a], 1u);
    a = k.y - lo; if ((unsigned)a < (unsigned)CHK) atomicAdd(&cnt[a], 1u);
    a = k.z - lo; if ((unsigned)a < (unsigned)CHK) atomicAdd(&cnt[a], 1u);
    a = k.w - lo; if ((unsigned)a < (unsigned)CHK) atomicAdd(&cnt[a], 1u);
  }
  __syncthreads();
  unsigned* p = partials + (long)sl * NN + lo;
  for (int i = threadIdx.x; i < CHK; i += 256) p[i] = cnt[i];
}

__global__ __launch_bounds__(256) void deg_scan_kernel(
    const unsigned* __restrict__ pd, const unsigned* __restrict__ ps,
    int* __restrict__ row_ptr, int* __restrict__ bsum,
    float* __restrict__ inv_mean, float* __restrict__ inv_in,
    float* __restrict__ inv_out) {
  __shared__ int sh[256];
  int n = blockIdx.x * 256 + threadIdx.x;
  unsigned di = 0, dz = 0;
  if (n < NN) {
    #pragma unroll 8
    for (int sl = 0; sl < NSL; ++sl) {
      di += pd[(long)sl * NN + n];
      dz += ps[(long)sl * NN + n];
    }
    float fdi = fmaxf((float)di, 1.f), fdz = fmaxf((float)dz, 1.f);
    inv_mean[n] = 1.f / fdi;
    inv_in[n]  = rsqrtf(fdi);
    inv_out[n] = rsqrtf(fdz);
  }
  int v = (n < NN) ? (int)di : 0;
  sh[threadIdx.x] = v;
  __syncthreads();
  #pragma unroll
  for (int off = 1; off < 256; off <<= 1) {
    int tv = (threadIdx.x >= off) ? sh[threadIdx.x - off] : 0;
    __syncthreads();
    sh[threadIdx.x] += tv;
    __syncthreads();
  }
  if (n < NN) row_ptr[n] = sh[threadIdx.x] - v;
  if (threadIdx.x == 255) bsum[blockIdx.x] = sh[255];
}

__global__ __launch_bounds__(256) void scan_block_kernel(const int* __restrict__ counts,
                                                         int* excl, int* bsum, int n) {
  __shared__ int sh[256];
  int i = blockIdx.x * 256 + threadIdx.x;
  int v = (i < n) ? counts[i] : 0;
  sh[threadIdx.x] = v;
  __syncthreads();
  #pragma unroll
  for (int off = 1; off < 256; off <<= 1) {
    int tv = (threadIdx.x >= off) ? sh[threadIdx.x - off] : 0;
    __syncthreads();
    sh[threadIdx.x] += tv;
    __syncthreads();
  }
  if (i < n) excl[i] = sh[threadIdx.x] - v;
  if (threadIdx.x == 255 && bsum) bsum[blockIdx.x] = sh[255];
}

__global__ void cursor_init_kernel(const int* __restrict__ row_ptr, const int* __restrict__ bsum,
                                   const unsigned* __restrict__ pd,
                                   unsigned* __restrict__ cur0,
                                   const float* __restrict__ inv_mean,
                                   const float* __restrict__ inv_in,
                                   int4* __restrict__ nodeinfo) {
  int n = blockIdx.x * 256 + threadIdx.x;
  if (n >= NN) return;
  unsigned start = (unsigned)(row_ptr[n] + bsum[n >> 8]);
  unsigned run = start;
  #pragma unroll 8
  for (int sl = 0; sl < NSL; ++sl) {
    cur0[(long)sl * NN + n] = run;
    run += pd[(long)sl * NN + n];
  }
  nodeinfo[n] = make_int4((int)start, (int)run,
                          __float_as_int(inv_mean[n]), __float_as_int(inv_in[n]));
}

__global__ __launch_bounds__(256) void fill_partial_kernel(
    const int4* __restrict__ dst4, const int4* __restrict__ src4,
    const unsigned* __restrict__ cur0, int* __restrict__ col) {
  __shared__ unsigned cur[CHK];
  const int chunk = blockIdx.x & 3;
  const int sl = blockIdx.x >> 2;
  const int lo = chunk * CHK;
  const unsigned* c0 = cur0 + (long)sl * NN + lo;
  for (int i = threadIdx.x; i < CHK; i += 256) cur[i] = c0[i];
  __syncthreads();
  const int base4 = sl * (ESL / 4);
  for (int i = threadIdx.x; i < ESL / 4; i += 256) {
    int4 d = dst4[base4 + i];
    int4 s = src4[base4 + i];
    int a;
    a = d.x - lo; if ((unsigned)a < (unsigned)CHK) col[atomicAdd(&cur[a], 1u)] = s.x;
    a = d.y - lo; if ((unsigned)a < (unsigned)CHK) col[atomicAdd(&cur[a], 1u)] = s.y;
    a = d.z - lo; if ((unsigned)a < (unsigned)CHK) col[atomicAdd(&cur[a], 1u)] = s.z;
    a = d.w - lo; if ((unsigned)a < (unsigned)CHK) col[atomicAdd(&cur[a], 1u)] = s.w;
  }
}

// ---------------- SpMM over feature-sliced fp16 table (4 slices x 32 feats) ----------------
// 3.2 MB/slice -> L2-resident (slice pinned to XCD-pair via blockIdx&7).
// Wave = (node, slice); lane = e16*4 + q4: 4 consecutive lanes cover one 64B row,
// 16 edges per gather instruction. fp16 accumulate; halving butterfly (masks 4,8,16)
// + plain add (mask 32); 32 lanes store 2B each into one 64B segment.

__global__ __launch_bounds__(256) void spmm32s_kernel(
    const int4* __restrict__ nodeinfo, const int* __restrict__ cols,
    const __half* __restrict__ xs, int useW,
    __half* __restrict__ outh) {
  const int t = threadIdx.x;
  const int lane = t & 63;
  const int wv = t >> 6;
  const int b = blockIdx.x;
  const int xcd = b & 7;
  const int slice = xcd >> 1;
  const int sub = xcd & 1;
  const int node = (b >> 3) * 8 + wv * 2 + sub;   // exact cover: NN = 6250*8
  const int e16 = lane >> 2;     // edge slot (0..15)
  const int q4 = lane & 3;       // 16B chunk of the 64B row
  const __half* xb = xs + (long)slice * NN * 32 + q4 * 8;
  int4 ni = nodeinfo[node];
  const int e0 = ni.x, end = ni.y;
  const float d = __int_as_float(useW ? ni.w : ni.z);
  const __half2 z2 = __float2half2_rn(0.f);
  __half2 A0 = z2, A1 = z2, A2 = z2, A3 = z2;
  int e = e0;
  for (; e + 16 <= end; e += 16) {
    int s = cols[e + e16];
    f32x4 v = *(const f32x4*)(xb + (unsigned)s * 32u);
    const __half2* h = (const __half2*)&v;
    A0 = __hadd2(A0, h[0]); A1 = __hadd2(A1, h[1]);
    A2 = __hadd2(A2, h[2]); A3 = __hadd2(A3, h[3]);
  }
  if (e < end) {                 // tail: <16 edges, per-lane predicated
    int ee = e + e16;
    if (ee < end) {
      int s = cols[ee];
      f32x4 v = *(const f32x4*)(xb + (unsigned)s * 32u);
      const __half2* h = (const __half2*)&v;
      A0 = __hadd2(A0, h[0]); A1 = __hadd2(A1, h[1]);
      A2 = __hadd2(A2, h[2]); A3 = __hadd2(A3, h[3]);
    }
  }
  float2 p0 = __half22float2(A0), p1 = __half22float2(A1);
  float2 p2 = __half22float2(A2), p3 = __half22float2(A3);
  float f0 = p0.x, f1 = p0.y, f2 = p1.x, f3 = p1.y;
  float f4 = p2.x, f5 = p2.y, f6 = p3.x, f7 = p3.y;
  // halving butterfly over e16 bits (lane bits 2,3,4), then plain add over bit 5
  {
    bool hi = (lane & 4) != 0;
    float t0 = hi ? f0 : f4, t1 = hi ? f1 : f5, t2 = hi ? f2 : f6, t3 = hi ? f3 : f7;
    t0 = __shfl_xor(t0, 4, 64); t1 = __shfl_xor(t1, 4, 64);
    t2 = __shfl_xor(t2, 4, 64); t3 = __shfl_xor(t3, 4, 64);
    f0 = (hi ? f4 : f0) + t0; f1 = (hi ? f5 : f1) + t1;
    f2 = (hi ? f6 : f2) + t2; f3 = (hi ? f7 : f3) + t3;
  }
  {
    bool hi = (lane & 8) != 0;
    float t0 = hi ? f0 : f2, t1 = hi ? f1 : f3;
    t0 = __shfl_xor(t0, 8, 64); t1 = __shfl_xor(t1, 8, 64);
    f0 = (hi ? f2 : f0) + t0; f1 = (hi ? f3 : f1) + t1;
  }
  float fin;
  {
    bool hi = (lane & 16) != 0;
    float t0 = hi ? f0 : f1;
    t0 = __shfl_xor(t0, 16, 64);
    fin = (hi ? f1 : f0) + t0;
  }
  fin += __shfl_xor(fin, 32, 64);
  if (lane < 32) {
    // feature bit2=lane.b2, bit1=lane.b3, bit0=lane.b4 (halving keep-order)
    int foff = q4 * 8 + ((lane >> 2) & 1) * 4 + ((lane >> 3) & 1) * 2 + ((lane >> 4) & 1);
    outh[((long)slice * NN + node) * 32 + foff] = __float2half(fin * d);
  }
}

// ---------------- fused weight prepack: all fp32 W -> fp16 MFMA fragments ----------------

constexpr int SZ256 = 8 * 8 * 512;   // K=256, NTP=8
constexpr int SZ128 = 4 * 8 * 512;   // K=128, NTP=8
constexpr int SZOUT = 4 * 4 * 512;   // K=128, NTP=4
constexpr int PK_TOTAL = 3 * SZ256 + 3 * SZ128 + SZOUT;

__global__ __launch_bounds__(256) void prepack_all_kernel(
    const float* __restrict__ w_in, const float* __restrict__ agg_w,
    const float* __restrict__ at1, const float* __restrict__ gc_w,
    const float* __restrict__ out_w, ushort* __restrict__ outbase) {
  int idx = blockIdx.x * 256 + threadIdx.x;
  if (idx >= PK_TOTAL) return;
  const float* W; int N, ldw, NTpad, local; ushort* outp;
  if (idx < 3 * SZ256) {
    int s = idx / SZ256; local = idx - s * SZ256;
    W = (s == 0) ? w_in : ((s == 1) ? agg_w : at1);
    N = HF; ldw = HF; NTpad = 8;
    outp = outbase + s * SZ256;
  } else if (idx < 3 * SZ256 + 3 * SZ128) {
    int r = idx - 3 * SZ256; int s = r / SZ128; local = r - s * SZ128;
    W = gc_w + (long)s * HF * HF; N = HF; ldw = HF; NTpad = 8;
    outp = outbase + 3 * SZ256 + s * SZ128;
  } else {
    local = idx - 3 * SZ256 - 3 * SZ128;
    W = out_w; N = CC; ldw = CC; NTpad = 4;
    outp = outbase + 3 * SZ256 + 3 * SZ128;
  }
  int j    = local & 7;
  int lane = (local >> 3) & 63;
  int rest = local >> 9;
  int nt = rest % NTpad;
  int kc = rest / NTpad;
  int k = kc * 32 + (lane >> 4) * 8 + j;
  int n = nt * 16 + (lane & 15);
  float w = (n < N) ? W[(long)k * ldw + n] : 0.f;
  outp[local] = __half_as_ushort(__float2half(w));
}

// ---------------- fp16 MFMA GEMM: out = epi( [A1|A2] @ W + bias ) ----------------
// Block = 64 rows x 128 cols, 4 waves; wave = 16 rows x NT*16 cols (782 blocks).
// A loads fully hoisted. ASRC=0: A fp32 row-major. ASRC=1: A fp16 sliced [k>>5][NN][32].
// EPI_ATTN: full attention fused in epilogue.

template<int KC, int NT, int NTP, int EPI, int H16, int ASRC, int OUTM>
__global__ __launch_bounds__(256) void mgemm_kernel(
    const void* __restrict__ A1, int lda1,
    const void* __restrict__ A2,
    const ushort* __restrict__ Bf,
    const float* __restrict__ bias,
    const float* __restrict__ g, const float* __restrict__ be,
    const float* __restrict__ mu, const float* __restrict__ va,
    const __half* __restrict__ resp,
    float* __restrict__ outf, __half* __restrict__ outh, int ldc, int Ncols,
    __half* __restrict__ x16, const float* __restrict__ rowscale) {
  const int t = threadIdx.x;
  const int lane = t & 63;
  const int wid = t >> 6;
  const int rowbase = blockIdx.x * 64 + wid * 16;
  const int arow = rowbase + (lane & 15);
  const int kgrp = (lane >> 4) * 8;
  const bool rowok = arow < NN;

  f32x4 acc[NT];
  #pragma unroll
  for (int n = 0; n < NT; ++n) acc[n] = (f32x4){0.f, 0.f, 0.f, 0.f};

  const f32x4 z4 = {0.f, 0.f, 0.f, 0.f};
  f32x4 fra[ASRC == 0 ? KC : 1], frb[ASRC == 0 ? KC : 1];
  uint4 areg[ASRC == 1 ? KC : 1];
  if (ASRC == 0) {
    #pragma unroll
    for (int kc = 0; kc < KC; ++kc) {
      const float* p = (const float*)A1 + (long)arow * lda1 + kc * 32 + kgrp;
      fra[kc] = rowok ? *(const f32x4*)p : z4;
      frb[kc] = rowok ? *(const f32x4*)(p + 4) : z4;
    }
  } else {
    #pragma unroll
    for (int kc = 0; kc < KC; ++kc) {
      const bool second = (KC == 8) && (kc >= 4);
      const ushort* At = (const ushort*)(second ? A2 : A1);
      int k0 = (second ? (kc - 4) : kc) * 32 + kgrp;
      const ushort* p = At + ((long)(k0 >> 5) * NN + arow) * 32 + (k0 & 31);
      areg[kc] = rowok ? *(const uint4*)p : make_uint4(0, 0, 0, 0);
    }
  }

  #pragma unroll
  for (int kc = 0; kc < KC; ++kc) {
    f16x8 av;
    if (ASRC == 0) {
      #pragma unroll
      for (int j = 0; j < 4; ++j) {
        av[j]     = (_Float16)fra[kc][j];
        av[j + 4] = (_Float16)frb[kc][j];
      }
    } else {
      union { uint4 u; f16x8 v; } cv;
      cv.u = areg[kc];
      av = cv.v;
    }
    const ushort* bp = Bf + ((long)kc * NTP * 64 + lane) * 8;
    #pragma unroll
    for (int nt = 0; nt < NT; ++nt) {
      union { uint4 u; f16x8 v; } bv;
      bv.u = *(const uint4*)(bp + (long)nt * 512);
      acc[nt] = __builtin_amdgcn_mfma_f32_16x16x32_f16(av, bv.v, acc[nt], 0, 0, 0);
    }
  }

  const int colg = lane & 15;
  const int rsub = (lane >> 4) * 4;

  if (EPI == EPI_ATTN) {
    float part0 = 0.f, part1 = 0.f, part2 = 0.f, part3 = 0.f;
    #pragma unroll
    for (int nt = 0; nt < NT; ++nt) {
      int c = nt * 16 + colg;
      float w2v = g[c];
      float bb = bias[c];
      part0 = fmaf(fmaxf(acc[nt][0] + bb, 0.f), w2v, part0);
      part1 = fmaf(fmaxf(acc[nt][1] + bb, 0.f), w2v, part1);
      part2 = fmaf(fmaxf(acc[nt][2] + bb, 0.f), w2v, part2);
      part3 = fmaf(fmaxf(acc[nt][3] + bb, 0.f), w2v, part3);
    }
    #pragma unroll
    for (int m = 1; m <= 8; m <<= 1) {
      part0 += __shfl_xor(part0, m, 64);
      part1 += __shfl_xor(part1, m, 64);
      part2 += __shfl_xor(part2, m, 64);
      part3 += __shfl_xor(part3, m, 64);
    }
    const float b2v = be[0];
    float s0 = 1.f / (1.f + __expf(-(part0 + b2v)));
    float s1 = 1.f / (1.f + __expf(-(part1 + b2v)));
    float s2 = 1.f / (1.f + __expf(-(part2 + b2v)));
    float s3 = 1.f / (1.f + __expf(-(part3 + b2v)));
    const __half* h0t = (const __half*)A1;
    const __half* aggt = (const __half*)A2;
    #pragma unroll
    for (int nt = 0; nt < NT; ++nt) {
      int c = nt * 16 + colg;
      #pragma unroll
      for (int i = 0; i < 4; ++i) {
        int r = rowbase + rsub + i;
        if (r >= NN) continue;
        long sidx = ((long)(c >> 5) * NN + r) * 32 + (c & 31);
        float sv = (i == 0) ? s0 : ((i == 1) ? s1 : ((i == 2) ? s2 : s3));
        float h = __half2float(h0t[sidx]) + __half2float(aggt[sidx]) * sv;
        x16[sidx] = __float2half(h * rowscale[r]);
      }
    }
    return;
  }

  #pragma unroll
  for (int nt = 0; nt < NT; ++nt) {
    int c = nt * 16 + colg;
    if (c >= Ncols) continue;
    float bb = bias ? bias[c] : 0.f;
    float scale = 1.f, shift = 0.f;
    if (EPI == EPI_BN || EPI == EPI_BN_RES) {
      scale = g[c] * rsqrtf(va[c] + EPSV);
      shift = be[c] - mu[c] * scale;
    }
    #pragma unroll
    for (int i = 0; i < 4; ++i) {
      int r = rowbase + rsub + i;
      if (r >= NN) continue;
      long sidx = ((long)(c >> 5) * NN + r) * 32 + (c & 31);
      float v = acc[nt][i] + bb;
      if (EPI == EPI_RELU) {
        v = fmaxf(v, 0.f);
      } else if (EPI == EPI_BN || EPI == EPI_BN_RES) {
        v = fmaxf(v * scale + shift, 0.f);
        if (EPI == EPI_BN_RES) v += __half2float(resp[sidx]);
      }
      if (OUTM == 0) {
        outf[(long)r * ldc + c] = v;
      } else {
        outh[sidx] = __float2half(v);
        if (H16 == H16_SCALED) x16[sidx] = __float2half(v * rowscale[r]);
      }
    }
  }
}

// ---------------- launch ----------------

extern "C" void kernel_launch(void* const* d_in, const int* in_sizes, int n_in,
                              void* d_out, int out_size, void* d_ws, size_t ws_size,
                              hipStream_t stream) {
  const float* features = (const float*)d_in[0];
  const int*   src      = (const int*)d_in[1];
  const int*   dst      = (const int*)d_in[2];
  const float* w_in     = (const float*)d_in[3];
  const float* b_in     = (const float*)d_in[4];
  const float* gc_w     = (const float*)d_in[5];
  const float* gc_b     = (const float*)d_in[6];
  const float* bn_gamma = (const float*)d_in[7];
  const float* bn_beta  = (const float*)d_in[8];
  const float* bn_mean  = (const float*)d_in[9];
  const float* bn_var   = (const float*)d_in[10];
  const float* attn_w1  = (const float*)d_in[11];
  const float* attn_b1  = (const float*)d_in[12];
  const float* attn_w2  = (const float*)d_in[13];
  const float* attn_b2  = (const float*)d_in[14];
  const float* agg_w    = (const float*)d_in[15];
  const float* agg_b    = (const float*)d_in[16];
  const float* out_w    = (const float*)d_in[17];
  const float* out_b    = (const float*)d_in[18];
  float* out = (float*)d_out;

  float* fbase = (float*)d_ws;
  float* inv_mean = fbase;
  float* inv_in   = inv_mean + NN;
  float* inv_out  = inv_in + NN;
  int* row_ptr = (int*)(inv_out + NN);   // NN+16
  int* bsum    = row_ptr + NN + 16;      // 256
  int* col     = bsum + 256;             // EE
  int4* nodeinfo = (int4*)(col + EE);    // NN

  // packed fp16 weights (contiguous: win, agg, at1, gc0..2, ow)
  ushort* pk = (ushort*)(nodeinfo + NN);
  ushort* win_f = pk;
  ushort* agg_f = pk + SZ256;
  ushort* at1_f = pk + 2 * SZ256;
  ushort* gcf0  = pk + 3 * SZ256;
  ushort* gcf1  = gcf0 + SZ128;
  ushort* gcf2  = gcf1 + SZ128;
  ushort* ow_f  = gcf2 + SZ128;

  // fp16 activation pools, sliced [4][NN][32]
  __half* T0 = (__half*)(ow_f + SZOUT);  // h0 -> rst1
  __half* T1 = T0 + NH;                  // neigh / spmm rst
  __half* T2 = T1 + NH;                  // agg -> rst0 -> rst2
  __half* X16 = T2 + NH;                 // scaled gather table

  // preprocessing scratch aliased into T0/T1 (dead before their first writes)
  unsigned* pd   = (unsigned*)T0;              // NSL*NN
  unsigned* ps   = pd + (long)NSL * NN;
  unsigned* cur0 = ps + (long)NSL * NN;

  dim3 b256(256);
  const int gN = (NN + 255) / 256;
  const int gblocks = (NN + 63) / 64;     // 782
  const int gspmm = (NN / 8) * 8;         // 50000
  const int gpre = NSL * 4;

  // graph preprocessing (no global atomics)
  count_partial2_kernel<<<2 * gpre, b256, 0, stream>>>(
      (const int4*)dst, (const int4*)src, pd, ps);
  deg_scan_kernel<<<gN, b256, 0, stream>>>(pd, ps, row_ptr, bsum, inv_mean, inv_in, inv_out);
  scan_block_kernel<<<1, b256, 0, stream>>>(bsum, bsum, nullptr, gN);
  cursor_init_kernel<<<gN, b256, 0, stream>>>(row_ptr, bsum, pd, cur0, inv_mean, inv_in, nodeinfo);
  fill_partial_kernel<<<gpre, b256, 0, stream>>>((const int4*)dst, (const int4*)src, cur0, col);

  // all weight prepack in one launch
  prepack_all_kernel<<<(PK_TOTAL + 255) / 256, b256, 0, stream>>>(
      w_in, agg_w, attn_w1, gc_w, out_w, pk);

  // #1: h0 = relu(features @ w_in + b_in) -> T0
  mgemm_kernel<8, 8, 8, EPI_RELU, H16_NONE, 0, 1><<<gblocks, b256, 0, stream>>>(
      features, INF_, nullptr, win_f, b_in,
      nullptr, nullptr, nullptr, nullptr, nullptr,
      nullptr, T0, HF, HF, nullptr, nullptr);
  // spmm1: neigh = mean-agg(h0) -> T1
  spmm32s_kernel<<<gspmm, b256, 0, stream>>>(nodeinfo, col, T0, 0, T1);
  // #2: agg = relu([h0|neigh] @ agg_w + agg_b) -> T2
  mgemm_kernel<8, 8, 8, EPI_RELU, H16_NONE, 1, 1><<<gblocks, b256, 0, stream>>>(
      T0, 0, T1, agg_f, agg_b,
      nullptr, nullptr, nullptr, nullptr, nullptr,
      nullptr, T2, HF, HF, nullptr, nullptr);
  // #3 (fused attn): a = relu([h0|agg]@w1+b1); s = sigmoid(a@w2+b2);
  //                  X16 = (h0 + agg*s) * inv_out
  mgemm_kernel<8, 8, 8, EPI_ATTN, H16_NONE, 1, 1><<<gblocks, b256, 0, stream>>>(
      T0, 0, T2, at1_f, attn_b1,
      attn_w2, attn_b2, nullptr, nullptr, nullptr,
      nullptr, nullptr, HF, HF, X16, inv_out);

  // layer 0: spmm(X16) -> T1 ; rst0 = relu(BN(T1@gc0+b0)) -> T2 (+X16 scaled)
  spmm32s_kernel<<<gspmm, b256, 0, stream>>>(nodeinfo, col, X16, 1, T1);
  mgemm_kernel<4, 8, 8, EPI_BN, H16_SCALED, 1, 1><<<gblocks, b256, 0, stream>>>(
      T1, 0, nullptr, gcf0, gc_b,
      bn_gamma, bn_beta, bn_mean, bn_var, nullptr,
      nullptr, T2, HF, HF, X16, inv_out);
  // layer 1: spmm(X16) -> T1 ; rst1 = relu(BN(T1@gc1+b1)) + rst0 -> T0 (+X16 scaled)
  spmm32s_kernel<<<gspmm, b256, 0, stream>>>(nodeinfo, col, X16, 1, T1);
  mgemm_kernel<4, 8, 8, EPI_BN_RES, H16_SCALED, 1, 1><<<gblocks, b256, 0, stream>>>(
      T1, 0, nullptr, gcf1, gc_b + HF,
      bn_gamma + HF, bn_beta + HF, bn_mean + HF, bn_var + HF, T2,
      nullptr, T0, HF, HF, X16, inv_out);
  // layer 2: spmm(X16) -> T1 ; rst2 = relu(BN(T1@gc2+b2)) + rst1 -> T2
  spmm32s_kernel<<<gspmm, b256, 0, stream>>>(nodeinfo, col, X16, 1, T1);
  mgemm_kernel<4, 8, 8, EPI_BN_RES, H16_NONE, 1, 1><<<gblocks, b256, 0, stream>>>(
      T1, 0, nullptr, gcf2, gc_b + 2 * HF,
      bn_gamma + 2 * HF, bn_beta + 2 * HF, bn_mean + 2 * HF, bn_var + 2 * HF, T0,
      nullptr, T2, HF, HF, nullptr, nullptr);

  // out = rst2 @ out_w + out_b -> d_out (fp32)
  mgemm_kernel<4, 4, 4, EPI_NONE, H16_NONE, 1, 0><<<gblocks, b256, 0, stream>>>(
      T2, 0, nullptr, ow_f, out_b,
      nullptr, nullptr, nullptr, nullptr, nullptr,
      out, nullptr, CC, CC, nullptr, nullptr);
}

// Round 16
// 358.368 us; speedup vs baseline: 1.1476x; 1.1476x over previous
//
#include <hip/hip_runtime.h>
#include <hip/hip_fp16.h>
#include <math.h>

constexpr int NN  = 50000;   // nodes
constexpr int EE  = 800000;  // edges
constexpr int INF_ = 256;    // input feat
constexpr int HF  = 128;     // hidden
constexpr int CC  = 50;      // classes
constexpr long NH = (long)NN * HF;
constexpr int NSL = 32;          // edge slices (preprocessing)
constexpr int ESL = EE / NSL;    // 25000 edges per slice
constexpr int CHK = 12500;       // nodes per chunk (4 chunks), 50KB LDS
#define EPSV 1e-5f

enum { EPI_RELU = 0, EPI_NONE = 1, EPI_BN = 2, EPI_BN_RES = 3, EPI_ATTN = 4 };
enum { H16_NONE = 0, H16_SCALED = 2 };

typedef __attribute__((ext_vector_type(4))) float f32x4;
typedef __attribute__((ext_vector_type(8))) _Float16 f16x8;

// ---------------- graph preprocessing (atomic-free: LDS histograms) ----------------

__global__ __launch_bounds__(256) void count_partial2_kernel(
    const int4* __restrict__ dst4, const int4* __restrict__ src4,
    unsigned* __restrict__ pd, unsigned* __restrict__ ps) {
  __shared__ unsigned cnt[CHK];
  int bb = blockIdx.x;
  const int which = bb >> 7;
  bb &= 127;
  const int4* keys4 = which ? src4 : dst4;
  unsigned* partials = which ? ps : pd;
  const int chunk = bb & 3;
  const int sl = bb >> 2;
  for (int i = threadIdx.x; i < CHK; i += 256) cnt[i] = 0;
  __syncthreads();
  const int base4 = sl * (ESL / 4);
  const int lo = chunk * CHK;
  for (int i = threadIdx.x; i < ESL / 4; i += 256) {
    int4 k = keys4[base4 + i];
    int a;
    a = k.x - lo; if ((unsigned)a < (unsigned)CHK) atomicAdd(&cnt[a], 1u);
    a = k.y - lo; if ((unsigned)a < (unsigned)CHK) atomicAdd(&cnt[a], 1u);
    a = k.z - lo; if ((unsigned)a < (unsigned)CHK) atomicAdd(&cnt[a], 1u);
    a = k.w - lo; if ((unsigned)a < (unsigned)CHK) atomicAdd(&cnt[a], 1u);
  }
  __syncthreads();
  unsigned* p = partials + (long)sl * NN + lo;
  for (int i = threadIdx.x; i < CHK; i += 256) p[i] = cnt[i];
}

__global__ __launch_bounds__(256) void deg_scan_kernel(
    const unsigned* __restrict__ pd, const unsigned* __restrict__ ps,
    int* __restrict__ row_ptr, int* __restrict__ bsum,
    float* __restrict__ inv_mean, float* __restrict__ inv_in,
    float* __restrict__ inv_out) {
  __shared__ int sh[256];
  int n = blockIdx.x * 256 + threadIdx.x;
  unsigned di = 0, dz = 0;
  if (n < NN) {
    #pragma unroll 8
    for (int sl = 0; sl < NSL; ++sl) {
      di += pd[(long)sl * NN + n];
      dz += ps[(long)sl * NN + n];
    }
    float fdi = fmaxf((float)di, 1.f), fdz = fmaxf((float)dz, 1.f);
    inv_mean[n] = 1.f / fdi;
    inv_in[n]  = rsqrtf(fdi);
    inv_out[n] = rsqrtf(fdz);
  }
  int v = (n < NN) ? (int)di : 0;
  sh[threadIdx.x] = v;
  __syncthreads();
  #pragma unroll
  for (int off = 1; off < 256; off <<= 1) {
    int tv = (threadIdx.x >= off) ? sh[threadIdx.x - off] : 0;
    __syncthreads();
    sh[threadIdx.x] += tv;
    __syncthreads();
  }
  if (n < NN) row_ptr[n] = sh[threadIdx.x] - v;
  if (threadIdx.x == 255) bsum[blockIdx.x] = sh[255];
}

__global__ __launch_bounds__(256) void scan_block_kernel(const int* __restrict__ counts,
                                                         int* excl, int* bsum, int n) {
  __shared__ int sh[256];
  int i = blockIdx.x * 256 + threadIdx.x;
  int v = (i < n) ? counts[i] : 0;
  sh[threadIdx.x] = v;
  __syncthreads();
  #pragma unroll
  for (int off = 1; off < 256; off <<= 1) {
    int tv = (threadIdx.x >= off) ? sh[threadIdx.x - off] : 0;
    __syncthreads();
    sh[threadIdx.x] += tv;
    __syncthreads();
  }
  if (i < n) excl[i] = sh[threadIdx.x] - v;
  if (threadIdx.x == 255 && bsum) bsum[blockIdx.x] = sh[255];
}

__global__ void cursor_init_kernel(const int* __restrict__ row_ptr, const int* __restrict__ bsum,
                                   const unsigned* __restrict__ pd,
                                   unsigned* __restrict__ cur0,
                                   const float* __restrict__ inv_mean,
                                   const float* __restrict__ inv_in,
                                   int4* __restrict__ nodeinfo) {
  int n = blockIdx.x * 256 + threadIdx.x;
  if (n >= NN) return;
  unsigned start = (unsigned)(row_ptr[n] + bsum[n >> 8]);
  unsigned run = start;
  #pragma unroll 8
  for (int sl = 0; sl < NSL; ++sl) {
    cur0[(long)sl * NN + n] = run;
    run += pd[(long)sl * NN + n];
  }
  nodeinfo[n] = make_int4((int)start, (int)run,
                          __float_as_int(inv_mean[n]), __float_as_int(inv_in[n]));
}

__global__ __launch_bounds__(256) void fill_partial_kernel(
    const int4* __restrict__ dst4, const int4* __restrict__ src4,
    const unsigned* __restrict__ cur0, int* __restrict__ col) {
  __shared__ unsigned cur[CHK];
  const int chunk = blockIdx.x & 3;
  const int sl = blockIdx.x >> 2;
  const int lo = chunk * CHK;
  const unsigned* c0 = cur0 + (long)sl * NN + lo;
  for (int i = threadIdx.x; i < CHK; i += 256) cur[i] = c0[i];
  __syncthreads();
  const int base4 = sl * (ESL / 4);
  for (int i = threadIdx.x; i < ESL / 4; i += 256) {
    int4 d = dst4[base4 + i];
    int4 s = src4[base4 + i];
    int a;
    a = d.x - lo; if ((unsigned)a < (unsigned)CHK) col[atomicAdd(&cur[a], 1u)] = s.x;
    a = d.y - lo; if ((unsigned)a < (unsigned)CHK) col[atomicAdd(&cur[a], 1u)] = s.y;
    a = d.z - lo; if ((unsigned)a < (unsigned)CHK) col[atomicAdd(&cur[a], 1u)] = s.z;
    a = d.w - lo; if ((unsigned)a < (unsigned)CHK) col[atomicAdd(&cur[a], 1u)] = s.w;
  }
}

// ---------------- SpMM: 4 slices x 32 feats (L2-resident), 2 nodes per wave ----------------
// Wave = (node pair, slice); lane = npair*32 + e8*4 + q4.
// Each 32-lane half: 8 edges x 64B rows (4 consecutive lanes per row, coalesced).
// Loop count = ceil(max(deg0,deg1)/8), inactive lanes clamp+mask.
// 3-level halving butterfly within each half; all 64 lanes store (2 nodes x 32 feats).

__global__ __launch_bounds__(256) void spmm32p_kernel(
    const int4* __restrict__ nodeinfo, const int* __restrict__ cols,
    const __half* __restrict__ xs, int useW,
    __half* __restrict__ outh) {
  const int t = threadIdx.x;
  const int lane = t & 63;
  const int wv = t >> 6;
  const int b = blockIdx.x;
  const int xcd = b & 7;
  const int slice = xcd >> 1;
  const int sub = xcd & 1;
  const int npair = lane >> 5;
  const int node = (b >> 3) * 16 + sub * 8 + wv * 2 + npair;  // NN = 3125*16
  const int e8 = (lane >> 2) & 7;
  const int q4 = lane & 3;
  const __half* xb = xs + (long)slice * NN * 32 + q4 * 8;
  int4 ni = nodeinfo[node];
  const int e0 = ni.x, end = ni.y;
  const float d = __int_as_float(useW ? ni.w : ni.z);
  const int deg = end - e0;
  int dmax = deg > 0 ? deg : 0;
  {
    int od = __shfl_xor(dmax, 32, 64);
    dmax = dmax > od ? dmax : od;
  }
  const int kmax = (dmax + 7) >> 3;
  const int ecl = (end - 1) > 0 ? (end - 1) : 0;   // safe clamp index
  const __half2 z2 = __float2half2_rn(0.f);
  __half2 A0 = z2, A1 = z2, A2 = z2, A3 = z2;
  for (int k = 0; k < kmax; ++k) {
    int ee = e0 + k * 8 + e8;
    bool m = ee < end;
    int ec = m ? ee : ecl;
    int s = cols[ec];
    f32x4 v = *(const f32x4*)(xb + (unsigned)s * 32u);
    const __half2* h = (const __half2*)&v;
    A0 = __hadd2(A0, m ? h[0] : z2);
    A1 = __hadd2(A1, m ? h[1] : z2);
    A2 = __hadd2(A2, m ? h[2] : z2);
    A3 = __hadd2(A3, m ? h[3] : z2);
  }
  float2 p0 = __half22float2(A0), p1 = __half22float2(A1);
  float2 p2 = __half22float2(A2), p3 = __half22float2(A3);
  float f0 = p0.x, f1 = p0.y, f2 = p1.x, f3 = p1.y;
  float f4 = p2.x, f5 = p2.y, f6 = p3.x, f7 = p3.y;
  // halving butterfly over e8 bits (lane bits 2,3,4), within each 32-lane half
  {
    bool hi = (lane & 4) != 0;
    float t0 = hi ? f0 : f4, t1 = hi ? f1 : f5, t2 = hi ? f2 : f6, t3 = hi ? f3 : f7;
    t0 = __shfl_xor(t0, 4, 64); t1 = __shfl_xor(t1, 4, 64);
    t2 = __shfl_xor(t2, 4, 64); t3 = __shfl_xor(t3, 4, 64);
    f0 = (hi ? f4 : f0) + t0; f1 = (hi ? f5 : f1) + t1;
    f2 = (hi ? f6 : f2) + t2; f3 = (hi ? f7 : f3) + t3;
  }
  {
    bool hi = (lane & 8) != 0;
    float t0 = hi ? f0 : f2, t1 = hi ? f1 : f3;
    t0 = __shfl_xor(t0, 8, 64); t1 = __shfl_xor(t1, 8, 64);
    f0 = (hi ? f2 : f0) + t0; f1 = (hi ? f3 : f1) + t1;
  }
  float fin;
  {
    bool hi = (lane & 16) != 0;
    float t0 = hi ? f0 : f1;
    t0 = __shfl_xor(t0, 16, 64);
    fin = (hi ? f1 : f0) + t0;
  }
  // feature bit2=lane.b2, bit1=lane.b3, bit0=lane.b4 (halving keep-order)
  int foff = q4 * 8 + ((lane >> 2) & 1) * 4 + ((lane >> 3) & 1) * 2 + ((lane >> 4) & 1);
  outh[((long)slice * NN + node) * 32 + foff] = __float2half(fin * d);
}

// ---------------- fused weight prepack: all fp32 W -> fp16 MFMA fragments ----------------

constexpr int SZ256 = 8 * 8 * 512;   // K=256, NTP=8
constexpr int SZ128 = 4 * 8 * 512;   // K=128, NTP=8
constexpr int SZOUT = 4 * 4 * 512;   // K=128, NTP=4
constexpr int PK_TOTAL = 3 * SZ256 + 3 * SZ128 + SZOUT;

__global__ __launch_bounds__(256) void prepack_all_kernel(
    const float* __restrict__ w_in, const float* __restrict__ agg_w,
    const float* __restrict__ at1, const float* __restrict__ gc_w,
    const float* __restrict__ out_w, ushort* __restrict__ outbase) {
  int idx = blockIdx.x * 256 + threadIdx.x;
  if (idx >= PK_TOTAL) return;
  const float* W; int N, ldw, NTpad, local; ushort* outp;
  if (idx < 3 * SZ256) {
    int s = idx / SZ256; local = idx - s * SZ256;
    W = (s == 0) ? w_in : ((s == 1) ? agg_w : at1);
    N = HF; ldw = HF; NTpad = 8;
    outp = outbase + s * SZ256;
  } else if (idx < 3 * SZ256 + 3 * SZ128) {
    int r = idx - 3 * SZ256; int s = r / SZ128; local = r - s * SZ128;
    W = gc_w + (long)s * HF * HF; N = HF; ldw = HF; NTpad = 8;
    outp = outbase + 3 * SZ256 + s * SZ128;
  } else {
    local = idx - 3 * SZ256 - 3 * SZ128;
    W = out_w; N = CC; ldw = CC; NTpad = 4;
    outp = outbase + 3 * SZ256 + 3 * SZ128;
  }
  int j    = local & 7;
  int lane = (local >> 3) & 63;
  int rest = local >> 9;
  int nt = rest % NTpad;
  int kc = rest / NTpad;
  int k = kc * 32 + (lane >> 4) * 8 + j;
  int n = nt * 16 + (lane & 15);
  float w = (n < N) ? W[(long)k * ldw + n] : 0.f;
  outp[local] = __half_as_ushort(__float2half(w));
}

// ---------------- fp16 MFMA GEMM: out = epi( [A1|A2] @ W + bias ) ----------------
// Block = 64 rows x 128 cols, 4 waves; wave = 16 rows x NT*16 cols (782 blocks).
// A loads fully hoisted. ASRC=0: A fp32 row-major. ASRC=1: A fp16 sliced [k>>5][NN][32].
// EPI_ATTN: full attention fused in epilogue.

template<int KC, int NT, int NTP, int EPI, int H16, int ASRC, int OUTM>
__global__ __launch_bounds__(256) void mgemm_kernel(
    const void* __restrict__ A1, int lda1,
    const void* __restrict__ A2,
    const ushort* __restrict__ Bf,
    const float* __restrict__ bias,
    const float* __restrict__ g, const float* __restrict__ be,
    const float* __restrict__ mu, const float* __restrict__ va,
    const __half* __restrict__ resp,
    float* __restrict__ outf, __half* __restrict__ outh, int ldc, int Ncols,
    __half* __restrict__ x16, const float* __restrict__ rowscale) {
  const int t = threadIdx.x;
  const int lane = t & 63;
  const int wid = t >> 6;
  const int rowbase = blockIdx.x * 64 + wid * 16;
  const int arow = rowbase + (lane & 15);
  const int kgrp = (lane >> 4) * 8;
  const bool rowok = arow < NN;

  f32x4 acc[NT];
  #pragma unroll
  for (int n = 0; n < NT; ++n) acc[n] = (f32x4){0.f, 0.f, 0.f, 0.f};

  const f32x4 z4 = {0.f, 0.f, 0.f, 0.f};
  f32x4 fra[ASRC == 0 ? KC : 1], frb[ASRC == 0 ? KC : 1];
  uint4 areg[ASRC == 1 ? KC : 1];
  if (ASRC == 0) {
    #pragma unroll
    for (int kc = 0; kc < KC; ++kc) {
      const float* p = (const float*)A1 + (long)arow * lda1 + kc * 32 + kgrp;
      fra[kc] = rowok ? *(const f32x4*)p : z4;
      frb[kc] = rowok ? *(const f32x4*)(p + 4) : z4;
    }
  } else {
    #pragma unroll
    for (int kc = 0; kc < KC; ++kc) {
      const bool second = (KC == 8) && (kc >= 4);
      const ushort* At = (const ushort*)(second ? A2 : A1);
      int k0 = (second ? (kc - 4) : kc) * 32 + kgrp;
      const ushort* p = At + ((long)(k0 >> 5) * NN + arow) * 32 + (k0 & 31);
      areg[kc] = rowok ? *(const uint4*)p : make_uint4(0, 0, 0, 0);
    }
  }

  #pragma unroll
  for (int kc = 0; kc < KC; ++kc) {
    f16x8 av;
    if (ASRC == 0) {
      #pragma unroll
      for (int j = 0; j < 4; ++j) {
        av[j]     = (_Float16)fra[kc][j];
        av[j + 4] = (_Float16)frb[kc][j];
      }
    } else {
      union { uint4 u; f16x8 v; } cv;
      cv.u = areg[kc];
      av = cv.v;
    }
    const ushort* bp = Bf + ((long)kc * NTP * 64 + lane) * 8;
    #pragma unroll
    for (int nt = 0; nt < NT; ++nt) {
      union { uint4 u; f16x8 v; } bv;
      bv.u = *(const uint4*)(bp + (long)nt * 512);
      acc[nt] = __builtin_amdgcn_mfma_f32_16x16x32_f16(av, bv.v, acc[nt], 0, 0, 0);
    }
  }

  const int colg = lane & 15;
  const int rsub = (lane >> 4) * 4;

  if (EPI == EPI_ATTN) {
    float part0 = 0.f, part1 = 0.f, part2 = 0.f, part3 = 0.f;
    #pragma unroll
    for (int nt = 0; nt < NT; ++nt) {
      int c = nt * 16 + colg;
      float w2v = g[c];
      float bb = bias[c];
      part0 = fmaf(fmaxf(acc[nt][0] + bb, 0.f), w2v, part0);
      part1 = fmaf(fmaxf(acc[nt][1] + bb, 0.f), w2v, part1);
      part2 = fmaf(fmaxf(acc[nt][2] + bb, 0.f), w2v, part2);
      part3 = fmaf(fmaxf(acc[nt][3] + bb, 0.f), w2v, part3);
    }
    #pragma unroll
    for (int m = 1; m <= 8; m <<= 1) {
      part0 += __shfl_xor(part0, m, 64);
      part1 += __shfl_xor(part1, m, 64);
      part2 += __shfl_xor(part2, m, 64);
      part3 += __shfl_xor(part3, m, 64);
    }
    const float b2v = be[0];
    float s0 = 1.f / (1.f + __expf(-(part0 + b2v)));
    float s1 = 1.f / (1.f + __expf(-(part1 + b2v)));
    float s2 = 1.f / (1.f + __expf(-(part2 + b2v)));
    float s3 = 1.f / (1.f + __expf(-(part3 + b2v)));
    const __half* h0t = (const __half*)A1;
    const __half* aggt = (const __half*)A2;
    #pragma unroll
    for (int nt = 0; nt < NT; ++nt) {
      int c = nt * 16 + colg;
      #pragma unroll
      for (int i = 0; i < 4; ++i) {
        int r = rowbase + rsub + i;
        if (r >= NN) continue;
        long sidx = ((long)(c >> 5) * NN + r) * 32 + (c & 31);
        float sv = (i == 0) ? s0 : ((i == 1) ? s1 : ((i == 2) ? s2 : s3));
        float h = __half2float(h0t[sidx]) + __half2float(aggt[sidx]) * sv;
        x16[sidx] = __float2half(h * rowscale[r]);
      }
    }
    return;
  }

  #pragma unroll
  for (int nt = 0; nt < NT; ++nt) {
    int c = nt * 16 + colg;
    if (c >= Ncols) continue;
    float bb = bias ? bias[c] : 0.f;
    float scale = 1.f, shift = 0.f;
    if (EPI == EPI_BN || EPI == EPI_BN_RES) {
      scale = g[c] * rsqrtf(va[c] + EPSV);
      shift = be[c] - mu[c] * scale;
    }
    #pragma unroll
    for (int i = 0; i < 4; ++i) {
      int r = rowbase + rsub + i;
      if (r >= NN) continue;
      long sidx = ((long)(c >> 5) * NN + r) * 32 + (c & 31);
      float v = acc[nt][i] + bb;
      if (EPI == EPI_RELU) {
        v = fmaxf(v, 0.f);
      } else if (EPI == EPI_BN || EPI == EPI_BN_RES) {
        v = fmaxf(v * scale + shift, 0.f);
        if (EPI == EPI_BN_RES) v += __half2float(resp[sidx]);
      }
      if (OUTM == 0) {
        outf[(long)r * ldc + c] = v;
      } else {
        outh[sidx] = __float2half(v);
        if (H16 == H16_SCALED) x16[sidx] = __float2half(v * rowscale[r]);
      }
    }
  }
}

// ---------------- launch ----------------

extern "C" void kernel_launch(void* const* d_in, const int* in_sizes, int n_in,
                              void* d_out, int out_size, void* d_ws, size_t ws_size,
                              hipStream_t stream) {
  const float* features = (const float*)d_in[0];
  const int*   src      = (const int*)d_in[1];
  const int*   dst      = (const int*)d_in[2];
  const float* w_in     = (const float*)d_in[3];
  const float* b_in     = (const float*)d_in[4];
  const float* gc_w     = (const float*)d_in[5];
  const float* gc_b     = (const float*)d_in[6];
  const float* bn_gamma = (const float*)d_in[7];
  const float* bn_beta  = (const float*)d_in[8];
  const float* bn_mean  = (const float*)d_in[9];
  const float* bn_var   = (const float*)d_in[10];
  const float* attn_w1  = (const float*)d_in[11];
  const float* attn_b1  = (const float*)d_in[12];
  const float* attn_w2  = (const float*)d_in[13];
  const float* attn_b2  = (const float*)d_in[14];
  const float* agg_w    = (const float*)d_in[15];
  const float* agg_b    = (const float*)d_in[16];
  const float* out_w    = (const float*)d_in[17];
  const float* out_b    = (const float*)d_in[18];
  float* out = (float*)d_out;

  float* fbase = (float*)d_ws;
  float* inv_mean = fbase;
  float* inv_in   = inv_mean + NN;
  float* inv_out  = inv_in + NN;
  int* row_ptr = (int*)(inv_out + NN);   // NN+16
  int* bsum    = row_ptr + NN + 16;      // 256
  int* col     = bsum + 256;             // EE
  int4* nodeinfo = (int4*)(col + EE);    // NN

  // packed fp16 weights (contiguous: win, agg, at1, gc0..2, ow)
  ushort* pk = (ushort*)(nodeinfo + NN);
  ushort* win_f = pk;
  ushort* agg_f = pk + SZ256;
  ushort* at1_f = pk + 2 * SZ256;
  ushort* gcf0  = pk + 3 * SZ256;
  ushort* gcf1  = gcf0 + SZ128;
  ushort* gcf2  = gcf1 + SZ128;
  ushort* ow_f  = gcf2 + SZ128;

  // fp16 activation pools, sliced [4][NN][32]
  __half* T0 = (__half*)(ow_f + SZOUT);  // h0 -> rst1
  __half* T1 = T0 + NH;                  // neigh / spmm rst
  __half* T2 = T1 + NH;                  // agg -> rst0 -> rst2
  __half* X16 = T2 + NH;                 // scaled gather table

  // preprocessing scratch aliased into T0/T1 (dead before their first writes)
  unsigned* pd   = (unsigned*)T0;              // NSL*NN
  unsigned* ps   = pd + (long)NSL * NN;
  unsigned* cur0 = ps + (long)NSL * NN;

  dim3 b256(256);
  const int gN = (NN + 255) / 256;
  const int gblocks = (NN + 63) / 64;     // 782
  const int gspmm = (NN / 16) * 8;        // 25000
  const int gpre = NSL * 4;

  // graph preprocessing (no global atomics)
  count_partial2_kernel<<<2 * gpre, b256, 0, stream>>>(
      (const int4*)dst, (const int4*)src, pd, ps);
  deg_scan_kernel<<<gN, b256, 0, stream>>>(pd, ps, row_ptr, bsum, inv_mean, inv_in, inv_out);
  scan_block_kernel<<<1, b256, 0, stream>>>(bsum, bsum, nullptr, gN);
  cursor_init_kernel<<<gN, b256, 0, stream>>>(row_ptr, bsum, pd, cur0, inv_mean, inv_in, nodeinfo);
  fill_partial_kernel<<<gpre, b256, 0, stream>>>((const int4*)dst, (const int4*)src, cur0, col);

  // all weight prepack in one launch
  prepack_all_kernel<<<(PK_TOTAL + 255) / 256, b256, 0, stream>>>(
      w_in, agg_w, attn_w1, gc_w, out_w, pk);

  // #1: h0 = relu(features @ w_in + b_in) -> T0
  mgemm_kernel<8, 8, 8, EPI_RELU, H16_NONE, 0, 1><<<gblocks, b256, 0, stream>>>(
      features, INF_, nullptr, win_f, b_in,
      nullptr, nullptr, nullptr, nullptr, nullptr,
      nullptr, T0, HF, HF, nullptr, nullptr);
  // spmm1: neigh = mean-agg(h0) -> T1
  spmm32p_kernel<<<gspmm, b256, 0, stream>>>(nodeinfo, col, T0, 0, T1);
  // #2: agg = relu([h0|neigh] @ agg_w + agg_b) -> T2
  mgemm_kernel<8, 8, 8, EPI_RELU, H16_NONE, 1, 1><<<gblocks, b256, 0, stream>>>(
      T0, 0, T1, agg_f, agg_b,
      nullptr, nullptr, nullptr, nullptr, nullptr,
      nullptr, T2, HF, HF, nullptr, nullptr);
  // #3 (fused attn): a = relu([h0|agg]@w1+b1); s = sigmoid(a@w2+b2);
  //                  X16 = (h0 + agg*s) * inv_out
  mgemm_kernel<8, 8, 8, EPI_ATTN, H16_NONE, 1, 1><<<gblocks, b256, 0, stream>>>(
      T0, 0, T2, at1_f, attn_b1,
      attn_w2, attn_b2, nullptr, nullptr, nullptr,
      nullptr, nullptr, HF, HF, X16, inv_out);

  // layer 0: spmm(X16) -> T1 ; rst0 = relu(BN(T1@gc0+b0)) -> T2 (+X16 scaled)
  spmm32p_kernel<<<gspmm, b256, 0, stream>>>(nodeinfo, col, X16, 1, T1);
  mgemm_kernel<4, 8, 8, EPI_BN, H16_SCALED, 1, 1><<<gblocks, b256, 0, stream>>>(
      T1, 0, nullptr, gcf0, gc_b,
      bn_gamma, bn_beta, bn_mean, bn_var, nullptr,
      nullptr, T2, HF, HF, X16, inv_out);
  // layer 1: spmm(X16) -> T1 ; rst1 = relu(BN(T1@gc1+b1)) + rst0 -> T0 (+X16 scaled)
  spmm32p_kernel<<<gspmm, b256, 0, stream>>>(nodeinfo, col, X16, 1, T1);
  mgemm_kernel<4, 8, 8, EPI_BN_RES, H16_SCALED, 1, 1><<<gblocks, b256, 0, stream>>>(
      T1, 0, nullptr, gcf1, gc_b + HF,
      bn_gamma + HF, bn_beta + HF, bn_mean + HF, bn_var + HF, T2,
      nullptr, T0, HF, HF, X16, inv_out);
  // layer 2: spmm(X16) -> T1 ; rst2 = relu(BN(T1@gc2+b2)) + rst1 -> T2
  spmm32p_kernel<<<gspmm, b256, 0, stream>>>(nodeinfo, col, X16, 1, T1);
  mgemm_kernel<4, 8, 8, EPI_BN_RES, H16_NONE, 1, 1><<<gblocks, b256, 0, stream>>>(
      T1, 0, nullptr, gcf2, gc_b + 2 * HF,
      bn_gamma + 2 * HF, bn_beta + 2 * HF, bn_mean + 2 * HF, bn_var + 2 * HF, T0,
      nullptr, T2, HF, HF, nullptr, nullptr);

  // out = rst2 @ out_w + out_b -> d_out (fp32)
  mgemm_kernel<4, 4, 4, EPI_NONE, H16_NONE, 1, 0><<<gblocks, b256, 0, stream>>>(
      T2, 0, nullptr, ow_f, out_b,
      nullptr, nullptr, nullptr, nullptr, nullptr,
      out, nullptr, CC, CC, nullptr, nullptr);
}

// Round 17
// 336.614 us; speedup vs baseline: 1.2217x; 1.0646x over previous
//
#include <hip/hip_runtime.h>
#include <hip/hip_fp16.h>
#include <math.h>

constexpr int NN  = 50000;   // nodes
constexpr int EE  = 800000;  // edges
constexpr int INF_ = 256;    // input feat
constexpr int HF  = 128;     // hidden
constexpr int CC  = 50;      // classes
constexpr long NH = (long)NN * HF;
constexpr int NSL = 32;          // edge slices (preprocessing)
constexpr int ESL = EE / NSL;    // 25000 edges per slice
constexpr int CHK = 12500;       // nodes per chunk (4 chunks), 50KB LDS
#define EPSV 1e-5f

enum { EPI_RELU = 0, EPI_NONE = 1, EPI_BN = 2, EPI_BN_RES = 3, EPI_ATTN = 4 };
enum { H16_NONE = 0, H16_SCALED = 2 };

typedef __attribute__((ext_vector_type(4))) float f32x4;
typedef __attribute__((ext_vector_type(8))) _Float16 f16x8;

// ---------------- graph preprocessing (atomic-free: LDS histograms) ----------------

__global__ __launch_bounds__(256) void count_partial2_kernel(
    const int4* __restrict__ dst4, const int4* __restrict__ src4,
    unsigned* __restrict__ pd, unsigned* __restrict__ ps) {
  __shared__ unsigned cnt[CHK];
  int bb = blockIdx.x;
  const int which = bb >> 7;
  bb &= 127;
  const int4* keys4 = which ? src4 : dst4;
  unsigned* partials = which ? ps : pd;
  const int chunk = bb & 3;
  const int sl = bb >> 2;
  for (int i = threadIdx.x; i < CHK; i += 256) cnt[i] = 0;
  __syncthreads();
  const int base4 = sl * (ESL / 4);
  const int lo = chunk * CHK;
  for (int i = threadIdx.x; i < ESL / 4; i += 256) {
    int4 k = keys4[base4 + i];
    int a;
    a = k.x - lo; if ((unsigned)a < (unsigned)CHK) atomicAdd(&cnt[a], 1u);
    a = k.y - lo; if ((unsigned)a < (unsigned)CHK) atomicAdd(&cnt[a], 1u);
    a = k.z - lo; if ((unsigned)a < (unsigned)CHK) atomicAdd(&cnt[a], 1u);
    a = k.w - lo; if ((unsigned)a < (unsigned)CHK) atomicAdd(&cnt[a], 1u);
  }
  __syncthreads();
  unsigned* p = partials + (long)sl * NN + lo;
  for (int i = threadIdx.x; i < CHK; i += 256) p[i] = cnt[i];
}

__global__ __launch_bounds__(256) void deg_scan_kernel(
    const unsigned* __restrict__ pd, const unsigned* __restrict__ ps,
    int* __restrict__ row_ptr, int* __restrict__ bsum,
    float* __restrict__ inv_mean, float* __restrict__ inv_in,
    float* __restrict__ inv_out) {
  __shared__ int sh[256];
  int n = blockIdx.x * 256 + threadIdx.x;
  unsigned di = 0, dz = 0;
  if (n < NN) {
    #pragma unroll 8
    for (int sl = 0; sl < NSL; ++sl) {
      di += pd[(long)sl * NN + n];
      dz += ps[(long)sl * NN + n];
    }
    float fdi = fmaxf((float)di, 1.f), fdz = fmaxf((float)dz, 1.f);
    inv_mean[n] = 1.f / fdi;
    inv_in[n]  = rsqrtf(fdi);
    inv_out[n] = rsqrtf(fdz);
  }
  int v = (n < NN) ? (int)di : 0;
  sh[threadIdx.x] = v;
  __syncthreads();
  #pragma unroll
  for (int off = 1; off < 256; off <<= 1) {
    int tv = (threadIdx.x >= off) ? sh[threadIdx.x - off] : 0;
    __syncthreads();
    sh[threadIdx.x] += tv;
    __syncthreads();
  }
  if (n < NN) row_ptr[n] = sh[threadIdx.x] - v;
  if (threadIdx.x == 255) bsum[blockIdx.x] = sh[255];
}

__global__ __launch_bounds__(256) void scan_block_kernel(const int* __restrict__ counts,
                                                         int* excl, int* bsum, int n) {
  __shared__ int sh[256];
  int i = blockIdx.x * 256 + threadIdx.x;
  int v = (i < n) ? counts[i] : 0;
  sh[threadIdx.x] = v;
  __syncthreads();
  #pragma unroll
  for (int off = 1; off < 256; off <<= 1) {
    int tv = (threadIdx.x >= off) ? sh[threadIdx.x - off] : 0;
    __syncthreads();
    sh[threadIdx.x] += tv;
    __syncthreads();
  }
  if (i < n) excl[i] = sh[threadIdx.x] - v;
  if (threadIdx.x == 255 && bsum) bsum[blockIdx.x] = sh[255];
}

__global__ void cursor_init_kernel(const int* __restrict__ row_ptr, const int* __restrict__ bsum,
                                   const unsigned* __restrict__ pd,
                                   unsigned* __restrict__ cur0,
                                   const float* __restrict__ inv_mean,
                                   const float* __restrict__ inv_in,
                                   int4* __restrict__ nodeinfo) {
  int n = blockIdx.x * 256 + threadIdx.x;
  if (n >= NN) return;
  unsigned start = (unsigned)(row_ptr[n] + bsum[n >> 8]);
  unsigned run = start;
  #pragma unroll 8
  for (int sl = 0; sl < NSL; ++sl) {
    cur0[(long)sl * NN + n] = run;
    run += pd[(long)sl * NN + n];
  }
  nodeinfo[n] = make_int4((int)start, (int)run,
                          __float_as_int(inv_mean[n]), __float_as_int(inv_in[n]));
}

__global__ __launch_bounds__(256) void fill_partial_kernel(
    const int4* __restrict__ dst4, const int4* __restrict__ src4,
    const unsigned* __restrict__ cur0, int* __restrict__ col) {
  __shared__ unsigned cur[CHK];
  const int chunk = blockIdx.x & 3;
  const int sl = blockIdx.x >> 2;
  const int lo = chunk * CHK;
  const unsigned* c0 = cur0 + (long)sl * NN + lo;
  for (int i = threadIdx.x; i < CHK; i += 256) cur[i] = c0[i];
  __syncthreads();
  const int base4 = sl * (ESL / 4);
  for (int i = threadIdx.x; i < ESL / 4; i += 256) {
    int4 d = dst4[base4 + i];
    int4 s = src4[base4 + i];
    int a;
    a = d.x - lo; if ((unsigned)a < (unsigned)CHK) col[atomicAdd(&cur[a], 1u)] = s.x;
    a = d.y - lo; if ((unsigned)a < (unsigned)CHK) col[atomicAdd(&cur[a], 1u)] = s.y;
    a = d.z - lo; if ((unsigned)a < (unsigned)CHK) col[atomicAdd(&cur[a], 1u)] = s.z;
    a = d.w - lo; if ((unsigned)a < (unsigned)CHK) col[atomicAdd(&cur[a], 1u)] = s.w;
  }
}

// ---------------- SpMM: 4 slices x 32 feats (L2-resident), 2 nodes per wave ----------------
// Wave = (node pair, slice); lane = npair*32 + e8*4 + q4.
// Edge loop unrolled x2 with independent gather pairs (2 cols + 2 gathers in flight,
// separate accumulator sets) -> one latency exposure for the modal degree (<=16).

__global__ __launch_bounds__(256) void spmm32p_kernel(
    const int4* __restrict__ nodeinfo, const int* __restrict__ cols,
    const __half* __restrict__ xs, int useW,
    __half* __restrict__ outh) {
  const int t = threadIdx.x;
  const int lane = t & 63;
  const int wv = t >> 6;
  const int b = blockIdx.x;
  const int xcd = b & 7;
  const int slice = xcd >> 1;
  const int sub = xcd & 1;
  const int npair = lane >> 5;
  const int node = (b >> 3) * 16 + sub * 8 + wv * 2 + npair;  // NN = 3125*16
  const int e8 = (lane >> 2) & 7;
  const int q4 = lane & 3;
  const __half* xb = xs + (long)slice * NN * 32 + q4 * 8;
  int4 ni = nodeinfo[node];
  const int e0 = ni.x, end = ni.y;
  const float d = __int_as_float(useW ? ni.w : ni.z);
  const int deg = end - e0;
  int dmax = deg > 0 ? deg : 0;
  {
    int od = __shfl_xor(dmax, 32, 64);
    dmax = dmax > od ? dmax : od;
  }
  const int kmax = (dmax + 7) >> 3;
  const int ecl = (end - 1) > 0 ? (end - 1) : 0;   // safe clamp index
  const __half2 z2 = __float2half2_rn(0.f);
  __half2 A0 = z2, A1 = z2, A2 = z2, A3 = z2;
  __half2 B0 = z2, B1 = z2, B2 = z2, B3 = z2;
  int k = 0;
  for (; k + 2 <= kmax; k += 2) {
    int ee0 = e0 + k * 8 + e8;
    int ee1 = ee0 + 8;
    bool m0 = ee0 < end, m1 = ee1 < end;
    int s0 = cols[m0 ? ee0 : ecl];
    int s1 = cols[m1 ? ee1 : ecl];
    f32x4 v0 = *(const f32x4*)(xb + (unsigned)s0 * 32u);
    f32x4 v1 = *(const f32x4*)(xb + (unsigned)s1 * 32u);
    const __half2* h0 = (const __half2*)&v0;
    const __half2* h1 = (const __half2*)&v1;
    A0 = __hadd2(A0, m0 ? h0[0] : z2); A1 = __hadd2(A1, m0 ? h0[1] : z2);
    A2 = __hadd2(A2, m0 ? h0[2] : z2); A3 = __hadd2(A3, m0 ? h0[3] : z2);
    B0 = __hadd2(B0, m1 ? h1[0] : z2); B1 = __hadd2(B1, m1 ? h1[1] : z2);
    B2 = __hadd2(B2, m1 ? h1[2] : z2); B3 = __hadd2(B3, m1 ? h1[3] : z2);
  }
  if (k < kmax) {
    int ee = e0 + k * 8 + e8;
    bool m = ee < end;
    int s = cols[m ? ee : ecl];
    f32x4 v = *(const f32x4*)(xb + (unsigned)s * 32u);
    const __half2* h = (const __half2*)&v;
    A0 = __hadd2(A0, m ? h[0] : z2); A1 = __hadd2(A1, m ? h[1] : z2);
    A2 = __hadd2(A2, m ? h[2] : z2); A3 = __hadd2(A3, m ? h[3] : z2);
  }
  A0 = __hadd2(A0, B0); A1 = __hadd2(A1, B1);
  A2 = __hadd2(A2, B2); A3 = __hadd2(A3, B3);
  float2 p0 = __half22float2(A0), p1 = __half22float2(A1);
  float2 p2 = __half22float2(A2), p3 = __half22float2(A3);
  float f0 = p0.x, f1 = p0.y, f2 = p1.x, f3 = p1.y;
  float f4 = p2.x, f5 = p2.y, f6 = p3.x, f7 = p3.y;
  // halving butterfly over e8 bits (lane bits 2,3,4), within each 32-lane half
  {
    bool hi = (lane & 4) != 0;
    float t0 = hi ? f0 : f4, t1 = hi ? f1 : f5, t2 = hi ? f2 : f6, t3 = hi ? f3 : f7;
    t0 = __shfl_xor(t0, 4, 64); t1 = __shfl_xor(t1, 4, 64);
    t2 = __shfl_xor(t2, 4, 64); t3 = __shfl_xor(t3, 4, 64);
    f0 = (hi ? f4 : f0) + t0; f1 = (hi ? f5 : f1) + t1;
    f2 = (hi ? f6 : f2) + t2; f3 = (hi ? f7 : f3) + t3;
  }
  {
    bool hi = (lane & 8) != 0;
    float t0 = hi ? f0 : f2, t1 = hi ? f1 : f3;
    t0 = __shfl_xor(t0, 8, 64); t1 = __shfl_xor(t1, 8, 64);
    f0 = (hi ? f2 : f0) + t0; f1 = (hi ? f3 : f1) + t1;
  }
  float fin;
  {
    bool hi = (lane & 16) != 0;
    float t0 = hi ? f0 : f1;
    t0 = __shfl_xor(t0, 16, 64);
    fin = (hi ? f1 : f0) + t0;
  }
  // feature bit2=lane.b2, bit1=lane.b3, bit0=lane.b4 (halving keep-order)
  int foff = q4 * 8 + ((lane >> 2) & 1) * 4 + ((lane >> 3) & 1) * 2 + ((lane >> 4) & 1);
  outh[((long)slice * NN + node) * 32 + foff] = __float2half(fin * d);
}

// ---------------- fused weight prepack: all fp32 W -> fp16 MFMA fragments ----------------

constexpr int SZ256 = 8 * 8 * 512;   // K=256, NTP=8
constexpr int SZ128 = 4 * 8 * 512;   // K=128, NTP=8
constexpr int SZOUT = 4 * 4 * 512;   // K=128, NTP=4
constexpr int PK_TOTAL = 3 * SZ256 + 3 * SZ128 + SZOUT;

__global__ __launch_bounds__(256) void prepack_all_kernel(
    const float* __restrict__ w_in, const float* __restrict__ agg_w,
    const float* __restrict__ at1, const float* __restrict__ gc_w,
    const float* __restrict__ out_w, ushort* __restrict__ outbase) {
  int idx = blockIdx.x * 256 + threadIdx.x;
  if (idx >= PK_TOTAL) return;
  const float* W; int N, ldw, NTpad, local; ushort* outp;
  if (idx < 3 * SZ256) {
    int s = idx / SZ256; local = idx - s * SZ256;
    W = (s == 0) ? w_in : ((s == 1) ? agg_w : at1);
    N = HF; ldw = HF; NTpad = 8;
    outp = outbase + s * SZ256;
  } else if (idx < 3 * SZ256 + 3 * SZ128) {
    int r = idx - 3 * SZ256; int s = r / SZ128; local = r - s * SZ128;
    W = gc_w + (long)s * HF * HF; N = HF; ldw = HF; NTpad = 8;
    outp = outbase + 3 * SZ256 + s * SZ128;
  } else {
    local = idx - 3 * SZ256 - 3 * SZ128;
    W = out_w; N = CC; ldw = CC; NTpad = 4;
    outp = outbase + 3 * SZ256 + 3 * SZ128;
  }
  int j    = local & 7;
  int lane = (local >> 3) & 63;
  int rest = local >> 9;
  int nt = rest % NTpad;
  int kc = rest / NTpad;
  int k = kc * 32 + (lane >> 4) * 8 + j;
  int n = nt * 16 + (lane & 15);
  float w = (n < N) ? W[(long)k * ldw + n] : 0.f;
  outp[local] = __half_as_ushort(__float2half(w));
}

// ---------------- fp16 MFMA GEMM: out = epi( [A1|A2] @ W + bias ) ----------------

template<int KC, int NT, int NTP, int EPI, int H16, int ASRC, int OUTM>
__global__ __launch_bounds__(256) void mgemm_kernel(
    const void* __restrict__ A1, int lda1,
    const void* __restrict__ A2,
    const ushort* __restrict__ Bf,
    const float* __restrict__ bias,
    const float* __restrict__ g, const float* __restrict__ be,
    const float* __restrict__ mu, const float* __restrict__ va,
    const __half* __restrict__ resp,
    float* __restrict__ outf, __half* __restrict__ outh, int ldc, int Ncols,
    __half* __restrict__ x16, const float* __restrict__ rowscale) {
  const int t = threadIdx.x;
  const int lane = t & 63;
  const int wid = t >> 6;
  const int rowbase = blockIdx.x * 64 + wid * 16;
  const int arow = rowbase + (lane & 15);
  const int kgrp = (lane >> 4) * 8;
  const bool rowok = arow < NN;

  f32x4 acc[NT];
  #pragma unroll
  for (int n = 0; n < NT; ++n) acc[n] = (f32x4){0.f, 0.f, 0.f, 0.f};

  const f32x4 z4 = {0.f, 0.f, 0.f, 0.f};
  f32x4 fra[ASRC == 0 ? KC : 1], frb[ASRC == 0 ? KC : 1];
  uint4 areg[ASRC == 1 ? KC : 1];
  if (ASRC == 0) {
    #pragma unroll
    for (int kc = 0; kc < KC; ++kc) {
      const float* p = (const float*)A1 + (long)arow * lda1 + kc * 32 + kgrp;
      fra[kc] = rowok ? *(const f32x4*)p : z4;
      frb[kc] = rowok ? *(const f32x4*)(p + 4) : z4;
    }
  } else {
    #pragma unroll
    for (int kc = 0; kc < KC; ++kc) {
      const bool second = (KC == 8) && (kc >= 4);
      const ushort* At = (const ushort*)(second ? A2 : A1);
      int k0 = (second ? (kc - 4) : kc) * 32 + kgrp;
      const ushort* p = At + ((long)(k0 >> 5) * NN + arow) * 32 + (k0 & 31);
      areg[kc] = rowok ? *(const uint4*)p : make_uint4(0, 0, 0, 0);
    }
  }

  #pragma unroll
  for (int kc = 0; kc < KC; ++kc) {
    f16x8 av;
    if (ASRC == 0) {
      #pragma unroll
      for (int j = 0; j < 4; ++j) {
        av[j]     = (_Float16)fra[kc][j];
        av[j + 4] = (_Float16)frb[kc][j];
      }
    } else {
      union { uint4 u; f16x8 v; } cv;
      cv.u = areg[kc];
      av = cv.v;
    }
    const ushort* bp = Bf + ((long)kc * NTP * 64 + lane) * 8;
    #pragma unroll
    for (int nt = 0; nt < NT; ++nt) {
      union { uint4 u; f16x8 v; } bv;
      bv.u = *(const uint4*)(bp + (long)nt * 512);
      acc[nt] = __builtin_amdgcn_mfma_f32_16x16x32_f16(av, bv.v, acc[nt], 0, 0, 0);
    }
  }

  const int colg = lane & 15;
  const int rsub = (lane >> 4) * 4;

  if (EPI == EPI_ATTN) {
    float part0 = 0.f, part1 = 0.f, part2 = 0.f, part3 = 0.f;
    #pragma unroll
    for (int nt = 0; nt < NT; ++nt) {
      int c = nt * 16 + colg;
      float w2v = g[c];
      float bb = bias[c];
      part0 = fmaf(fmaxf(acc[nt][0] + bb, 0.f), w2v, part0);
      part1 = fmaf(fmaxf(acc[nt][1] + bb, 0.f), w2v, part1);
      part2 = fmaf(fmaxf(acc[nt][2] + bb, 0.f), w2v, part2);
      part3 = fmaf(fmaxf(acc[nt][3] + bb, 0.f), w2v, part3);
    }
    #pragma unroll
    for (int m = 1; m <= 8; m <<= 1) {
      part0 += __shfl_xor(part0, m, 64);
      part1 += __shfl_xor(part1, m, 64);
      part2 += __shfl_xor(part2, m, 64);
      part3 += __shfl_xor(part3, m, 64);
    }
    const float b2v = be[0];
    float s0 = 1.f / (1.f + __expf(-(part0 + b2v)));
    float s1 = 1.f / (1.f + __expf(-(part1 + b2v)));
    float s2 = 1.f / (1.f + __expf(-(part2 + b2v)));
    float s3 = 1.f / (1.f + __expf(-(part3 + b2v)));
    const __half* h0t = (const __half*)A1;
    const __half* aggt = (const __half*)A2;
    #pragma unroll
    for (int nt = 0; nt < NT; ++nt) {
      int c = nt * 16 + colg;
      #pragma unroll
      for (int i = 0; i < 4; ++i) {
        int r = rowbase + rsub + i;
        if (r >= NN) continue;
        long sidx = ((long)(c >> 5) * NN + r) * 32 + (c & 31);
        float sv = (i == 0) ? s0 : ((i == 1) ? s1 : ((i == 2) ? s2 : s3));
        float h = __half2float(h0t[sidx]) + __half2float(aggt[sidx]) * sv;
        x16[sidx] = __float2half(h * rowscale[r]);
      }
    }
    return;
  }

  #pragma unroll
  for (int nt = 0; nt < NT; ++nt) {
    int c = nt * 16 + colg;
    if (c >= Ncols) continue;
    float bb = bias ? bias[c] : 0.f;
    float scale = 1.f, shift = 0.f;
    if (EPI == EPI_BN || EPI == EPI_BN_RES) {
      scale = g[c] * rsqrtf(va[c] + EPSV);
      shift = be[c] - mu[c] * scale;
    }
    #pragma unroll
    for (int i = 0; i < 4; ++i) {
      int r = rowbase + rsub + i;
      if (r >= NN) continue;
      long sidx = ((long)(c >> 5) * NN + r) * 32 + (c & 31);
      float v = acc[nt][i] + bb;
      if (EPI == EPI_RELU) {
        v = fmaxf(v, 0.f);
      } else if (EPI == EPI_BN || EPI == EPI_BN_RES) {
        v = fmaxf(v * scale + shift, 0.f);
        if (EPI == EPI_BN_RES) v += __half2float(resp[sidx]);
      }
      if (OUTM == 0) {
        outf[(long)r * ldc + c] = v;
      } else {
        outh[sidx] = __float2half(v);
        if (H16 == H16_SCALED) x16[sidx] = __float2half(v * rowscale[r]);
      }
    }
  }
}

// ---------------- launch ----------------

extern "C" void kernel_launch(void* const* d_in, const int* in_sizes, int n_in,
                              void* d_out, int out_size, void* d_ws, size_t ws_size,
                              hipStream_t stream) {
  const float* features = (const float*)d_in[0];
  const int*   src      = (const int*)d_in[1];
  const int*   dst      = (const int*)d_in[2];
  const float* w_in     = (const float*)d_in[3];
  const float* b_in     = (const float*)d_in[4];
  const float* gc_w     = (const float*)d_in[5];
  const float* gc_b     = (const float*)d_in[6];
  const float* bn_gamma = (const float*)d_in[7];
  const float* bn_beta  = (const float*)d_in[8];
  const float* bn_mean  = (const float*)d_in[9];
  const float* bn_var   = (const float*)d_in[10];
  const float* attn_w1  = (const float*)d_in[11];
  const float* attn_b1  = (const float*)d_in[12];
  const float* attn_w2  = (const float*)d_in[13];
  const float* attn_b2  = (const float*)d_in[14];
  const float* agg_w    = (const float*)d_in[15];
  const float* agg_b    = (const float*)d_in[16];
  const float* out_w    = (const float*)d_in[17];
  const float* out_b    = (const float*)d_in[18];
  float* out = (float*)d_out;

  float* fbase = (float*)d_ws;
  float* inv_mean = fbase;
  float* inv_in   = inv_mean + NN;
  float* inv_out  = inv_in + NN;
  int* row_ptr = (int*)(inv_out + NN);   // NN+16
  int* bsum    = row_ptr + NN + 16;      // 256
  int* col     = bsum + 256;             // EE
  int4* nodeinfo = (int4*)(col + EE);    // NN

  // packed fp16 weights (contiguous: win, agg, at1, gc0..2, ow)
  ushort* pk = (ushort*)(nodeinfo + NN);
  ushort* win_f = pk;
  ushort* agg_f = pk + SZ256;
  ushort* at1_f = pk + 2 * SZ256;
  ushort* gcf0  = pk + 3 * SZ256;
  ushort* gcf1  = gcf0 + SZ128;
  ushort* gcf2  = gcf1 + SZ128;
  ushort* ow_f  = gcf2 + SZ128;

  // fp16 activation pools, sliced [4][NN][32]
  __half* T0 = (__half*)(ow_f + SZOUT);  // h0 -> rst1
  __half* T1 = T0 + NH;                  // neigh / spmm rst
  __half* T2 = T1 + NH;                  // agg -> rst0 -> rst2
  __half* X16 = T2 + NH;                 // scaled gather table

  // preprocessing scratch aliased into T0/T1 (dead before their first writes)
  unsigned* pd   = (unsigned*)T0;              // NSL*NN
  unsigned* ps   = pd + (long)NSL * NN;
  unsigned* cur0 = ps + (long)NSL * NN;

  dim3 b256(256);
  const int gN = (NN + 255) / 256;
  const int gblocks = (NN + 63) / 64;     // 782
  const int gspmm = (NN / 16) * 8;        // 25000
  const int gpre = NSL * 4;

  // graph preprocessing (no global atomics)
  count_partial2_kernel<<<2 * gpre, b256, 0, stream>>>(
      (const int4*)dst, (const int4*)src, pd, ps);
  deg_scan_kernel<<<gN, b256, 0, stream>>>(pd, ps, row_ptr, bsum, inv_mean, inv_in, inv_out);
  scan_block_kernel<<<1, b256, 0, stream>>>(bsum, bsum, nullptr, gN);
  cursor_init_kernel<<<gN, b256, 0, stream>>>(row_ptr, bsum, pd, cur0, inv_mean, inv_in, nodeinfo);
  fill_partial_kernel<<<gpre, b256, 0, stream>>>((const int4*)dst, (const int4*)src, cur0, col);

  // all weight prepack in one launch
  prepack_all_kernel<<<(PK_TOTAL + 255) / 256, b256, 0, stream>>>(
      w_in, agg_w, attn_w1, gc_w, out_w, pk);

  // #1: h0 = relu(features @ w_in + b_in) -> T0
  mgemm_kernel<8, 8, 8, EPI_RELU, H16_NONE, 0, 1><<<gblocks, b256, 0, stream>>>(
      features, INF_, nullptr, win_f, b_in,
      nullptr, nullptr, nullptr, nullptr, nullptr,
      nullptr, T0, HF, HF, nullptr, nullptr);
  // spmm1: neigh = mean-agg(h0) -> T1
  spmm32p_kernel<<<gspmm, b256, 0, stream>>>(nodeinfo, col, T0, 0, T1);
  // #2: agg = relu([h0|neigh] @ agg_w + agg_b) -> T2
  mgemm_kernel<8, 8, 8, EPI_RELU, H16_NONE, 1, 1><<<gblocks, b256, 0, stream>>>(
      T0, 0, T1, agg_f, agg_b,
      nullptr, nullptr, nullptr, nullptr, nullptr,
      nullptr, T2, HF, HF, nullptr, nullptr);
  // #3 (fused attn): a = relu([h0|agg]@w1+b1); s = sigmoid(a@w2+b2);
  //                  X16 = (h0 + agg*s) * inv_out
  mgemm_kernel<8, 8, 8, EPI_ATTN, H16_NONE, 1, 1><<<gblocks, b256, 0, stream>>>(
      T0, 0, T2, at1_f, attn_b1,
      attn_w2, attn_b2, nullptr, nullptr, nullptr,
      nullptr, nullptr, HF, HF, X16, inv_out);

  // layer 0: spmm(X16) -> T1 ; rst0 = relu(BN(T1@gc0+b0)) -> T2 (+X16 scaled)
  spmm32p_kernel<<<gspmm, b256, 0, stream>>>(nodeinfo, col, X16, 1, T1);
  mgemm_kernel<4, 8, 8, EPI_BN, H16_SCALED, 1, 1><<<gblocks, b256, 0, stream>>>(
      T1, 0, nullptr, gcf0, gc_b,
      bn_gamma, bn_beta, bn_mean, bn_var, nullptr,
      nullptr, T2, HF, HF, X16, inv_out);
  // layer 1: spmm(X16) -> T1 ; rst1 = relu(BN(T1@gc1+b1)) + rst0 -> T0 (+X16 scaled)
  spmm32p_kernel<<<gspmm, b256, 0, stream>>>(nodeinfo, col, X16, 1, T1);
  mgemm_kernel<4, 8, 8, EPI_BN_RES, H16_SCALED, 1, 1><<<gblocks, b256, 0, stream>>>(
      T1, 0, nullptr, gcf1, gc_b + HF,
      bn_gamma + HF, bn_beta + HF, bn_mean + HF, bn_var + HF, T2,
      nullptr, T0, HF, HF, X16, inv_out);
  // layer 2: spmm(X16) -> T1 ; rst2 = relu(BN(T1@gc2+b2)) + rst1 -> T2
  spmm32p_kernel<<<gspmm, b256, 0, stream>>>(nodeinfo, col, X16, 1, T1);
  mgemm_kernel<4, 8, 8, EPI_BN_RES, H16_NONE, 1, 1><<<gblocks, b256, 0, stream>>>(
      T1, 0, nullptr, gcf2, gc_b + 2 * HF,
      bn_gamma + 2 * HF, bn_beta + 2 * HF, bn_mean + 2 * HF, bn_var + 2 * HF, T0,
      nullptr, T2, HF, HF, nullptr, nullptr);

  // out = rst2 @ out_w + out_b -> d_out (fp32)
  mgemm_kernel<4, 4, 4, EPI_NONE, H16_NONE, 1, 0><<<gblocks, b256, 0, stream>>>(
      T2, 0, nullptr, ow_f, out_b,
      nullptr, nullptr, nullptr, nullptr, nullptr,
      out, nullptr, CC, CC, nullptr, nullptr);
}

// Round 18
// 320.862 us; speedup vs baseline: 1.2817x; 1.0491x over previous
//
#include <hip/hip_runtime.h>
#include <hip/hip_fp16.h>
#include <math.h>

constexpr int NN  = 50000;   // nodes
constexpr int EE  = 800000;  // edges
constexpr int INF_ = 256;    // input feat
constexpr int HF  = 128;     // hidden
constexpr int CC  = 50;      // classes
constexpr long NH = (long)NN * HF;
constexpr int NSL = 32;          // edge slices (preprocessing)
constexpr int ESL = EE / NSL;    // 25000 edges per slice
constexpr int CHK = 12500;       // nodes per chunk (4 chunks), 50KB LDS
#define EPSV 1e-5f

enum { EPI_RELU = 0, EPI_NONE = 1, EPI_BN = 2, EPI_BN_RES = 3, EPI_ATTN = 4 };
enum { H16_NONE = 0, H16_SCALED = 2 };

typedef __attribute__((ext_vector_type(4))) float f32x4;
typedef __attribute__((ext_vector_type(8))) _Float16 f16x8;

// ---------------- graph preprocessing (atomic-free: LDS histograms) ----------------

__global__ __launch_bounds__(256) void count_partial2_kernel(
    const int4* __restrict__ dst4, const int4* __restrict__ src4,
    unsigned* __restrict__ pd, unsigned* __restrict__ ps) {
  __shared__ unsigned cnt[CHK];
  int bb = blockIdx.x;
  const int which = bb >> 7;
  bb &= 127;
  const int4* keys4 = which ? src4 : dst4;
  unsigned* partials = which ? ps : pd;
  const int chunk = bb & 3;
  const int sl = bb >> 2;
  for (int i = threadIdx.x; i < CHK; i += 256) cnt[i] = 0;
  __syncthreads();
  const int base4 = sl * (ESL / 4);
  const int lo = chunk * CHK;
  for (int i = threadIdx.x; i < ESL / 4; i += 256) {
    int4 k = keys4[base4 + i];
    int a;
    a = k.x - lo; if ((unsigned)a < (unsigned)CHK) atomicAdd(&cnt[a], 1u);
    a = k.y - lo; if ((unsigned)a < (unsigned)CHK) atomicAdd(&cnt[a], 1u);
    a = k.z - lo; if ((unsigned)a < (unsigned)CHK) atomicAdd(&cnt[a], 1u);
    a = k.w - lo; if ((unsigned)a < (unsigned)CHK) atomicAdd(&cnt[a], 1u);
  }
  __syncthreads();
  unsigned* p = partials + (long)sl * NN + lo;
  for (int i = threadIdx.x; i < CHK; i += 256) p[i] = cnt[i];
}

__global__ __launch_bounds__(256) void deg_scan_kernel(
    const unsigned* __restrict__ pd, const unsigned* __restrict__ ps,
    int* __restrict__ row_ptr, int* __restrict__ bsum,
    float* __restrict__ inv_mean, float* __restrict__ inv_in,
    float* __restrict__ inv_out) {
  __shared__ int sh[256];
  int n = blockIdx.x * 256 + threadIdx.x;
  unsigned di = 0, dz = 0;
  if (n < NN) {
    #pragma unroll 8
    for (int sl = 0; sl < NSL; ++sl) {
      di += pd[(long)sl * NN + n];
      dz += ps[(long)sl * NN + n];
    }
    float fdi = fmaxf((float)di, 1.f), fdz = fmaxf((float)dz, 1.f);
    inv_mean[n] = 1.f / fdi;
    inv_in[n]  = rsqrtf(fdi);
    inv_out[n] = rsqrtf(fdz);
  }
  int v = (n < NN) ? (int)di : 0;
  sh[threadIdx.x] = v;
  __syncthreads();
  #pragma unroll
  for (int off = 1; off < 256; off <<= 1) {
    int tv = (threadIdx.x >= off) ? sh[threadIdx.x - off] : 0;
    __syncthreads();
    sh[threadIdx.x] += tv;
    __syncthreads();
  }
  if (n < NN) row_ptr[n] = sh[threadIdx.x] - v;
  if (threadIdx.x == 255) bsum[blockIdx.x] = sh[255];
}

__global__ __launch_bounds__(256) void scan_block_kernel(const int* __restrict__ counts,
                                                         int* excl, int* bsum, int n) {
  __shared__ int sh[256];
  int i = blockIdx.x * 256 + threadIdx.x;
  int v = (i < n) ? counts[i] : 0;
  sh[threadIdx.x] = v;
  __syncthreads();
  #pragma unroll
  for (int off = 1; off < 256; off <<= 1) {
    int tv = (threadIdx.x >= off) ? sh[threadIdx.x - off] : 0;
    __syncthreads();
    sh[threadIdx.x] += tv;
    __syncthreads();
  }
  if (i < n) excl[i] = sh[threadIdx.x] - v;
  if (threadIdx.x == 255 && bsum) bsum[blockIdx.x] = sh[255];
}

__global__ void cursor_init_kernel(const int* __restrict__ row_ptr, const int* __restrict__ bsum,
                                   const unsigned* __restrict__ pd,
                                   unsigned* __restrict__ cur0,
                                   const float* __restrict__ inv_mean,
                                   const float* __restrict__ inv_in,
                                   int4* __restrict__ nodeinfo) {
  int n = blockIdx.x * 256 + threadIdx.x;
  if (n >= NN) return;
  unsigned start = (unsigned)(row_ptr[n] + bsum[n >> 8]);
  unsigned run = start;
  #pragma unroll 8
  for (int sl = 0; sl < NSL; ++sl) {
    cur0[(long)sl * NN + n] = run;
    run += pd[(long)sl * NN + n];
  }
  nodeinfo[n] = make_int4((int)start, (int)run,
                          __float_as_int(inv_mean[n]), __float_as_int(inv_in[n]));
}

__global__ __launch_bounds__(256) void fill_partial_kernel(
    const int4* __restrict__ dst4, const int4* __restrict__ src4,
    const unsigned* __restrict__ cur0, int* __restrict__ col) {
  __shared__ unsigned cur[CHK];
  const int chunk = blockIdx.x & 3;
  const int sl = blockIdx.x >> 2;
  const int lo = chunk * CHK;
  const unsigned* c0 = cur0 + (long)sl * NN + lo;
  for (int i = threadIdx.x; i < CHK; i += 256) cur[i] = c0[i];
  __syncthreads();
  const int base4 = sl * (ESL / 4);
  for (int i = threadIdx.x; i < ESL / 4; i += 256) {
    int4 d = dst4[base4 + i];
    int4 s = src4[base4 + i];
    int a;
    a = d.x - lo; if ((unsigned)a < (unsigned)CHK) col[atomicAdd(&cur[a], 1u)] = s.x;
    a = d.y - lo; if ((unsigned)a < (unsigned)CHK) col[atomicAdd(&cur[a], 1u)] = s.y;
    a = d.z - lo; if ((unsigned)a < (unsigned)CHK) col[atomicAdd(&cur[a], 1u)] = s.z;
    a = d.w - lo; if ((unsigned)a < (unsigned)CHK) col[atomicAdd(&cur[a], 1u)] = s.w;
  }
}

// ---------------- SpMM: 4 slices x 32 feats (L2-resident), 2 nodes per wave ----------------

__global__ __launch_bounds__(256) void spmm32p_kernel(
    const int4* __restrict__ nodeinfo, const int* __restrict__ cols,
    const __half* __restrict__ xs, int useW,
    __half* __restrict__ outh) {
  const int t = threadIdx.x;
  const int lane = t & 63;
  const int wv = t >> 6;
  const int b = blockIdx.x;
  const int xcd = b & 7;
  const int slice = xcd >> 1;
  const int sub = xcd & 1;
  const int npair = lane >> 5;
  const int node = (b >> 3) * 16 + sub * 8 + wv * 2 + npair;  // NN = 3125*16
  const int e8 = (lane >> 2) & 7;
  const int q4 = lane & 3;
  const __half* xb = xs + (long)slice * NN * 32 + q4 * 8;
  int4 ni = nodeinfo[node];
  const int e0 = ni.x, end = ni.y;
  const float d = __int_as_float(useW ? ni.w : ni.z);
  const int deg = end - e0;
  int dmax = deg > 0 ? deg : 0;
  {
    int od = __shfl_xor(dmax, 32, 64);
    dmax = dmax > od ? dmax : od;
  }
  const int kmax = (dmax + 7) >> 3;
  const int ecl = (end - 1) > 0 ? (end - 1) : 0;   // safe clamp index
  const __half2 z2 = __float2half2_rn(0.f);
  __half2 A0 = z2, A1 = z2, A2 = z2, A3 = z2;
  __half2 B0 = z2, B1 = z2, B2 = z2, B3 = z2;
  int k = 0;
  for (; k + 2 <= kmax; k += 2) {
    int ee0 = e0 + k * 8 + e8;
    int ee1 = ee0 + 8;
    bool m0 = ee0 < end, m1 = ee1 < end;
    int s0 = cols[m0 ? ee0 : ecl];
    int s1 = cols[m1 ? ee1 : ecl];
    f32x4 v0 = *(const f32x4*)(xb + (unsigned)s0 * 32u);
    f32x4 v1 = *(const f32x4*)(xb + (unsigned)s1 * 32u);
    const __half2* h0 = (const __half2*)&v0;
    const __half2* h1 = (const __half2*)&v1;
    A0 = __hadd2(A0, m0 ? h0[0] : z2); A1 = __hadd2(A1, m0 ? h0[1] : z2);
    A2 = __hadd2(A2, m0 ? h0[2] : z2); A3 = __hadd2(A3, m0 ? h0[3] : z2);
    B0 = __hadd2(B0, m1 ? h1[0] : z2); B1 = __hadd2(B1, m1 ? h1[1] : z2);
    B2 = __hadd2(B2, m1 ? h1[2] : z2); B3 = __hadd2(B3, m1 ? h1[3] : z2);
  }
  if (k < kmax) {
    int ee = e0 + k * 8 + e8;
    bool m = ee < end;
    int s = cols[m ? ee : ecl];
    f32x4 v = *(const f32x4*)(xb + (unsigned)s * 32u);
    const __half2* h = (const __half2*)&v;
    A0 = __hadd2(A0, m ? h[0] : z2); A1 = __hadd2(A1, m ? h[1] : z2);
    A2 = __hadd2(A2, m ? h[2] : z2); A3 = __hadd2(A3, m ? h[3] : z2);
  }
  A0 = __hadd2(A0, B0); A1 = __hadd2(A1, B1);
  A2 = __hadd2(A2, B2); A3 = __hadd2(A3, B3);
  float2 p0 = __half22float2(A0), p1 = __half22float2(A1);
  float2 p2 = __half22float2(A2), p3 = __half22float2(A3);
  float f0 = p0.x, f1 = p0.y, f2 = p1.x, f3 = p1.y;
  float f4 = p2.x, f5 = p2.y, f6 = p3.x, f7 = p3.y;
  {
    bool hi = (lane & 4) != 0;
    float t0 = hi ? f0 : f4, t1 = hi ? f1 : f5, t2 = hi ? f2 : f6, t3 = hi ? f3 : f7;
    t0 = __shfl_xor(t0, 4, 64); t1 = __shfl_xor(t1, 4, 64);
    t2 = __shfl_xor(t2, 4, 64); t3 = __shfl_xor(t3, 4, 64);
    f0 = (hi ? f4 : f0) + t0; f1 = (hi ? f5 : f1) + t1;
    f2 = (hi ? f6 : f2) + t2; f3 = (hi ? f7 : f3) + t3;
  }
  {
    bool hi = (lane & 8) != 0;
    float t0 = hi ? f0 : f2, t1 = hi ? f1 : f3;
    t0 = __shfl_xor(t0, 8, 64); t1 = __shfl_xor(t1, 8, 64);
    f0 = (hi ? f2 : f0) + t0; f1 = (hi ? f3 : f1) + t1;
  }
  float fin;
  {
    bool hi = (lane & 16) != 0;
    float t0 = hi ? f0 : f1;
    t0 = __shfl_xor(t0, 16, 64);
    fin = (hi ? f1 : f0) + t0;
  }
  int foff = q4 * 8 + ((lane >> 2) & 1) * 4 + ((lane >> 3) & 1) * 2 + ((lane >> 4) & 1);
  outh[((long)slice * NN + node) * 32 + foff] = __float2half(fin * d);
}

// ---------------- fused weight prepack: all fp32 W -> fp16 MFMA fragments ----------------

constexpr int SZ256 = 8 * 8 * 512;   // K=256, NTP=8
constexpr int SZ128 = 4 * 8 * 512;   // K=128, NTP=8
constexpr int SZOUT = 4 * 4 * 512;   // K=128, NTP=4
constexpr int PK_TOTAL = 3 * SZ256 + 3 * SZ128 + SZOUT;

__global__ __launch_bounds__(256) void prepack_all_kernel(
    const float* __restrict__ w_in, const float* __restrict__ agg_w,
    const float* __restrict__ at1, const float* __restrict__ gc_w,
    const float* __restrict__ out_w, ushort* __restrict__ outbase) {
  int idx = blockIdx.x * 256 + threadIdx.x;
  if (idx >= PK_TOTAL) return;
  const float* W; int N, ldw, NTpad, local; ushort* outp;
  if (idx < 3 * SZ256) {
    int s = idx / SZ256; local = idx - s * SZ256;
    W = (s == 0) ? w_in : ((s == 1) ? agg_w : at1);
    N = HF; ldw = HF; NTpad = 8;
    outp = outbase + s * SZ256;
  } else if (idx < 3 * SZ256 + 3 * SZ128) {
    int r = idx - 3 * SZ256; int s = r / SZ128; local = r - s * SZ128;
    W = gc_w + (long)s * HF * HF; N = HF; ldw = HF; NTpad = 8;
    outp = outbase + 3 * SZ256 + s * SZ128;
  } else {
    local = idx - 3 * SZ256 - 3 * SZ128;
    W = out_w; N = CC; ldw = CC; NTpad = 4;
    outp = outbase + 3 * SZ256 + 3 * SZ128;
  }
  int j    = local & 7;
  int lane = (local >> 3) & 63;
  int rest = local >> 9;
  int nt = rest % NTpad;
  int kc = rest / NTpad;
  int k = kc * 32 + (lane >> 4) * 8 + j;
  int n = nt * 16 + (lane & 15);
  float w = (n < N) ? W[(long)k * ldw + n] : 0.f;
  outp[local] = __half_as_ushort(__float2half(w));
}

// ---------------- fp16 MFMA GEMM: out = epi( [A1|A2] @ W + bias ) ----------------
// COLSPLIT=0: block = 64 rows, 4 waves = 4 row-groups x full 128 cols (NT=8).
// COLSPLIT=1: block = 32 rows, 4 waves = 2 row-groups x 2 col-halves (NT=4),
//             grid 2x -> 6250 waves (~6.1/SIMD) for latency hiding.

template<int KC, int NT, int NTP, int EPI, int H16, int ASRC, int OUTM, int COLSPLIT>
__global__ __launch_bounds__(256) void mgemm_kernel(
    const void* __restrict__ A1, int lda1,
    const void* __restrict__ A2,
    const ushort* __restrict__ Bf,
    const float* __restrict__ bias,
    const float* __restrict__ g, const float* __restrict__ be,
    const float* __restrict__ mu, const float* __restrict__ va,
    const __half* __restrict__ resp,
    float* __restrict__ outf, __half* __restrict__ outh, int ldc, int Ncols,
    __half* __restrict__ x16, const float* __restrict__ rowscale) {
  const int t = threadIdx.x;
  const int lane = t & 63;
  const int wid = t >> 6;
  const int rowbase = COLSPLIT ? (blockIdx.x * 32 + (wid >> 1) * 16)
                               : (blockIdx.x * 64 + wid * 16);
  const int colbase = COLSPLIT ? ((wid & 1) * NT * 16) : 0;
  const int arow = rowbase + (lane & 15);
  const int kgrp = (lane >> 4) * 8;
  const bool rowok = arow < NN;

  f32x4 acc[NT];
  #pragma unroll
  for (int n = 0; n < NT; ++n) acc[n] = (f32x4){0.f, 0.f, 0.f, 0.f};

  const f32x4 z4 = {0.f, 0.f, 0.f, 0.f};
  f32x4 fra[ASRC == 0 ? KC : 1], frb[ASRC == 0 ? KC : 1];
  uint4 areg[ASRC == 1 ? KC : 1];
  if (ASRC == 0) {
    #pragma unroll
    for (int kc = 0; kc < KC; ++kc) {
      const float* p = (const float*)A1 + (long)arow * lda1 + kc * 32 + kgrp;
      fra[kc] = rowok ? *(const f32x4*)p : z4;
      frb[kc] = rowok ? *(const f32x4*)(p + 4) : z4;
    }
  } else {
    #pragma unroll
    for (int kc = 0; kc < KC; ++kc) {
      const bool second = (KC == 8) && (kc >= 4);
      const ushort* At = (const ushort*)(second ? A2 : A1);
      int k0 = (second ? (kc - 4) : kc) * 32 + kgrp;
      const ushort* p = At + ((long)(k0 >> 5) * NN + arow) * 32 + (k0 & 31);
      areg[kc] = rowok ? *(const uint4*)p : make_uint4(0, 0, 0, 0);
    }
  }

  #pragma unroll
  for (int kc = 0; kc < KC; ++kc) {
    f16x8 av;
    if (ASRC == 0) {
      #pragma unroll
      for (int j = 0; j < 4; ++j) {
        av[j]     = (_Float16)fra[kc][j];
        av[j + 4] = (_Float16)frb[kc][j];
      }
    } else {
      union { uint4 u; f16x8 v; } cv;
      cv.u = areg[kc];
      av = cv.v;
    }
    const ushort* bp = Bf + ((long)kc * NTP * 64 + lane) * 8 + (long)colbase * 32;
    #pragma unroll
    for (int nt = 0; nt < NT; ++nt) {
      union { uint4 u; f16x8 v; } bv;
      bv.u = *(const uint4*)(bp + (long)nt * 512);
      acc[nt] = __builtin_amdgcn_mfma_f32_16x16x32_f16(av, bv.v, acc[nt], 0, 0, 0);
    }
  }

  const int colg = lane & 15;
  const int rsub = (lane >> 4) * 4;

  if (EPI == EPI_ATTN) {
    float part0 = 0.f, part1 = 0.f, part2 = 0.f, part3 = 0.f;
    #pragma unroll
    for (int nt = 0; nt < NT; ++nt) {
      int c = nt * 16 + colg;
      float w2v = g[c];
      float bb = bias[c];
      part0 = fmaf(fmaxf(acc[nt][0] + bb, 0.f), w2v, part0);
      part1 = fmaf(fmaxf(acc[nt][1] + bb, 0.f), w2v, part1);
      part2 = fmaf(fmaxf(acc[nt][2] + bb, 0.f), w2v, part2);
      part3 = fmaf(fmaxf(acc[nt][3] + bb, 0.f), w2v, part3);
    }
    #pragma unroll
    for (int m = 1; m <= 8; m <<= 1) {
      part0 += __shfl_xor(part0, m, 64);
      part1 += __shfl_xor(part1, m, 64);
      part2 += __shfl_xor(part2, m, 64);
      part3 += __shfl_xor(part3, m, 64);
    }
    const float b2v = be[0];
    float s0 = 1.f / (1.f + __expf(-(part0 + b2v)));
    float s1 = 1.f / (1.f + __expf(-(part1 + b2v)));
    float s2 = 1.f / (1.f + __expf(-(part2 + b2v)));
    float s3 = 1.f / (1.f + __expf(-(part3 + b2v)));
    const __half* h0t = (const __half*)A1;
    const __half* aggt = (const __half*)A2;
    #pragma unroll
    for (int nt = 0; nt < NT; ++nt) {
      int c = nt * 16 + colg;
      #pragma unroll
      for (int i = 0; i < 4; ++i) {
        int r = rowbase + rsub + i;
        if (r >= NN) continue;
        long sidx = ((long)(c >> 5) * NN + r) * 32 + (c & 31);
        float sv = (i == 0) ? s0 : ((i == 1) ? s1 : ((i == 2) ? s2 : s3));
        float h = __half2float(h0t[sidx]) + __half2float(aggt[sidx]) * sv;
        x16[sidx] = __float2half(h * rowscale[r]);
      }
    }
    return;
  }

  #pragma unroll
  for (int nt = 0; nt < NT; ++nt) {
    int c = colbase + nt * 16 + colg;
    if (c >= Ncols) continue;
    float bb = bias ? bias[c] : 0.f;
    float scale = 1.f, shift = 0.f;
    if (EPI == EPI_BN || EPI == EPI_BN_RES) {
      scale = g[c] * rsqrtf(va[c] + EPSV);
      shift = be[c] - mu[c] * scale;
    }
    #pragma unroll
    for (int i = 0; i < 4; ++i) {
      int r = rowbase + rsub + i;
      if (r >= NN) continue;
      long sidx = ((long)(c >> 5) * NN + r) * 32 + (c & 31);
      float v = acc[nt][i] + bb;
      if (EPI == EPI_RELU) {
        v = fmaxf(v, 0.f);
      } else if (EPI == EPI_BN || EPI == EPI_BN_RES) {
        v = fmaxf(v * scale + shift, 0.f);
        if (EPI == EPI_BN_RES) v += __half2float(resp[sidx]);
      }
      if (OUTM == 0) {
        outf[(long)r * ldc + c] = v;
      } else {
        outh[sidx] = __float2half(v);
        if (H16 == H16_SCALED) x16[sidx] = __float2half(v * rowscale[r]);
      }
    }
  }
}

// ---------------- launch ----------------

extern "C" void kernel_launch(void* const* d_in, const int* in_sizes, int n_in,
                              void* d_out, int out_size, void* d_ws, size_t ws_size,
                              hipStream_t stream) {
  const float* features = (const float*)d_in[0];
  const int*   src      = (const int*)d_in[1];
  const int*   dst      = (const int*)d_in[2];
  const float* w_in     = (const float*)d_in[3];
  const float* b_in     = (const float*)d_in[4];
  const float* gc_w     = (const float*)d_in[5];
  const float* gc_b     = (const float*)d_in[6];
  const float* bn_gamma = (const float*)d_in[7];
  const float* bn_beta  = (const float*)d_in[8];
  const float* bn_mean  = (const float*)d_in[9];
  const float* bn_var   = (const float*)d_in[10];
  const float* attn_w1  = (const float*)d_in[11];
  const float* attn_b1  = (const float*)d_in[12];
  const float* attn_w2  = (const float*)d_in[13];
  const float* attn_b2  = (const float*)d_in[14];
  const float* agg_w    = (const float*)d_in[15];
  const float* agg_b    = (const float*)d_in[16];
  const float* out_w    = (const float*)d_in[17];
  const float* out_b    = (const float*)d_in[18];
  float* out = (float*)d_out;

  float* fbase = (float*)d_ws;
  float* inv_mean = fbase;
  float* inv_in   = inv_mean + NN;
  float* inv_out  = inv_in + NN;
  int* row_ptr = (int*)(inv_out + NN);   // NN+16
  int* bsum    = row_ptr + NN + 16;      // 256
  int* col     = bsum + 256;             // EE
  int4* nodeinfo = (int4*)(col + EE);    // NN

  // packed fp16 weights (contiguous: win, agg, at1, gc0..2, ow)
  ushort* pk = (ushort*)(nodeinfo + NN);
  ushort* win_f = pk;
  ushort* agg_f = pk + SZ256;
  ushort* at1_f = pk + 2 * SZ256;
  ushort* gcf0  = pk + 3 * SZ256;
  ushort* gcf1  = gcf0 + SZ128;
  ushort* gcf2  = gcf1 + SZ128;
  ushort* ow_f  = gcf2 + SZ128;

  // fp16 activation pools, sliced [4][NN][32]
  __half* T0 = (__half*)(ow_f + SZOUT);  // h0 -> rst1
  __half* T1 = T0 + NH;                  // neigh / spmm rst
  __half* T2 = T1 + NH;                  // agg -> rst0 -> rst2
  __half* X16 = T2 + NH;                 // scaled gather table

  // preprocessing scratch aliased into T0/T1 (dead before their first writes)
  unsigned* pd   = (unsigned*)T0;              // NSL*NN
  unsigned* ps   = pd + (long)NSL * NN;
  unsigned* cur0 = ps + (long)NSL * NN;

  dim3 b256(256);
  const int gN = (NN + 255) / 256;
  const int gblocks = (NN + 63) / 64;     // 782 (NT=8 blocks)
  const int gsplit  = (NN + 31) / 32;     // 1563 (col-split blocks)
  const int gspmm = (NN / 16) * 8;        // 25000
  const int gpre = NSL * 4;

  // graph preprocessing (no global atomics)
  count_partial2_kernel<<<2 * gpre, b256, 0, stream>>>(
      (const int4*)dst, (const int4*)src, pd, ps);
  deg_scan_kernel<<<gN, b256, 0, stream>>>(pd, ps, row_ptr, bsum, inv_mean, inv_in, inv_out);
  scan_block_kernel<<<1, b256, 0, stream>>>(bsum, bsum, nullptr, gN);
  cursor_init_kernel<<<gN, b256, 0, stream>>>(row_ptr, bsum, pd, cur0, inv_mean, inv_in, nodeinfo);
  fill_partial_kernel<<<gpre, b256, 0, stream>>>((const int4*)dst, (const int4*)src, cur0, col);

  // all weight prepack in one launch
  prepack_all_kernel<<<(PK_TOTAL + 255) / 256, b256, 0, stream>>>(
      w_in, agg_w, attn_w1, gc_w, out_w, pk);

  // #1: h0 = relu(features @ w_in + b_in) -> T0  (col-split)
  mgemm_kernel<8, 4, 8, EPI_RELU, H16_NONE, 0, 1, 1><<<gsplit, b256, 0, stream>>>(
      features, INF_, nullptr, win_f, b_in,
      nullptr, nullptr, nullptr, nullptr, nullptr,
      nullptr, T0, HF, HF, nullptr, nullptr);
  // spmm1: neigh = mean-agg(h0) -> T1
  spmm32p_kernel<<<gspmm, b256, 0, stream>>>(nodeinfo, col, T0, 0, T1);
  // #2: agg = relu([h0|neigh] @ agg_w + agg_b) -> T2  (col-split)
  mgemm_kernel<8, 4, 8, EPI_RELU, H16_NONE, 1, 1, 1><<<gsplit, b256, 0, stream>>>(
      T0, 0, T1, agg_f, agg_b,
      nullptr, nullptr, nullptr, nullptr, nullptr,
      nullptr, T2, HF, HF, nullptr, nullptr);
  // #3 (fused attn): needs full row per wave -> NT=8, no col-split
  mgemm_kernel<8, 8, 8, EPI_ATTN, H16_NONE, 1, 1, 0><<<gblocks, b256, 0, stream>>>(
      T0, 0, T2, at1_f, attn_b1,
      attn_w2, attn_b2, nullptr, nullptr, nullptr,
      nullptr, nullptr, HF, HF, X16, inv_out);

  // layer 0: spmm(X16) -> T1 ; rst0 = relu(BN(T1@gc0+b0)) -> T2 (+X16)  (col-split)
  spmm32p_kernel<<<gspmm, b256, 0, stream>>>(nodeinfo, col, X16, 1, T1);
  mgemm_kernel<4, 4, 8, EPI_BN, H16_SCALED, 1, 1, 1><<<gsplit, b256, 0, stream>>>(
      T1, 0, nullptr, gcf0, gc_b,
      bn_gamma, bn_beta, bn_mean, bn_var, nullptr,
      nullptr, T2, HF, HF, X16, inv_out);
  // layer 1: spmm(X16) -> T1 ; rst1 = relu(BN(T1@gc1+b1)) + rst0 -> T0 (+X16)
  spmm32p_kernel<<<gspmm, b256, 0, stream>>>(nodeinfo, col, X16, 1, T1);
  mgemm_kernel<4, 4, 8, EPI_BN_RES, H16_SCALED, 1, 1, 1><<<gsplit, b256, 0, stream>>>(
      T1, 0, nullptr, gcf1, gc_b + HF,
      bn_gamma + HF, bn_beta + HF, bn_mean + HF, bn_var + HF, T2,
      nullptr, T0, HF, HF, X16, inv_out);
  // layer 2: spmm(X16) -> T1 ; rst2 = relu(BN(T1@gc2+b2)) + rst1 -> T2
  spmm32p_kernel<<<gspmm, b256, 0, stream>>>(nodeinfo, col, X16, 1, T1);
  mgemm_kernel<4, 4, 8, EPI_BN_RES, H16_NONE, 1, 1, 1><<<gsplit, b256, 0, stream>>>(
      T1, 0, nullptr, gcf2, gc_b + 2 * HF,
      bn_gamma + 2 * HF, bn_beta + 2 * HF, bn_mean + 2 * HF, bn_var + 2 * HF, T0,
      nullptr, T2, HF, HF, nullptr, nullptr);

  // out = rst2 @ out_w + out_b -> d_out (fp32; NT=4 covers 64 >= 50 cols)
  mgemm_kernel<4, 4, 4, EPI_NONE, H16_NONE, 1, 0, 0><<<gblocks, b256, 0, stream>>>(
      T2, 0, nullptr, ow_f, out_b,
      nullptr, nullptr, nullptr, nullptr, nullptr,
      out, nullptr, CC, CC, nullptr, nullptr);
}